// Round 9
// baseline (1814.453 us; speedup 1.0000x reference)
//
#include <hip/hip_runtime.h>
#include <hip/hip_cooperative_groups.h>
#include <math.h>

namespace cg = cooperative_groups;

// FieldlineGraphForecaster round 8: cooperative mega-kernel.
// enc -> ab -> [gather -> node]x4 -> dec fused into ONE cooperative launch
// with grid.sync() between phases (kills ~150us of launch gaps). Phase
// bodies are bit-identical ports of r7 kernels (absmax must stay 64).
// prep/sort remain small standalone kernels.

constexpr int H = 128;
constexpr int NTHR = 256;
constexpr int TE = 64;    // rows per MFMA tile
constexpr int TILE = 32;  // rows per fp32 (enc/dec) tile
constexpr int CHUNK = 16; // sorted edges per wave-chunk

using bf16x8 = __attribute__((ext_vector_type(8))) short;
using f32x4  = __attribute__((ext_vector_type(4))) float;

// Branchless GELU: A&S 7.1.26 erf (5-term), |eps|<=1.5e-7. DO NOT downgrade:
// 3-term (2.5e-5) fails the harness threshold (r6: absmax 80 > 78).
__device__ __forceinline__ float gelu_fast(float x) {
    const float u = fabsf(x) * 0.70710678118654752440f;
    const float t = __builtin_amdgcn_rcpf(fmaf(0.3275911f, u, 1.f));
    float p = fmaf(1.061405429f, t, -1.453152027f);
    p = fmaf(p, t, 1.421413741f);
    p = fmaf(p, t, -0.284496736f);
    p = fmaf(p, t, 0.254829592f);
    p = p * t;
    const float e = __expf(-u * u);
    float er = fmaf(-p, e, 1.f);  // erf(|x|/sqrt2)
    er = copysignf(er, x);
    return 0.5f * x * (1.f + er);
}

__device__ __forceinline__ unsigned short f2bf(float f) {
    unsigned int u = __builtin_bit_cast(unsigned int, f);
    u = (u + 0x7fffu + ((u >> 16) & 1u)) >> 16;
    return (unsigned short)u;
}

__device__ __forceinline__ float bf2f_lo(unsigned int v) {
    return __builtin_bit_cast(float, v << 16);
}
__device__ __forceinline__ float bf2f_hi(unsigned int v) {
    return __builtin_bit_cast(float, v & 0xffff0000u);
}

// ---- merged weight prep: eW1t, nW2t, nW1tc(top) in one kernel ------------
__global__ __launch_bounds__(NTHR) void prep_kernel(
    const float* __restrict__ eW1, const float* __restrict__ nW2,
    const float* __restrict__ nW1, unsigned short* __restrict__ eW1t,
    unsigned short* __restrict__ nW2t, unsigned short* __restrict__ nW1tc,
    int t1, int t2) {
    const int i = blockIdx.x * NTHR + threadIdx.x;
    if (i < t1) {
        const int per = 2 * H * H;
        const int l = i / per;
        const int r = i - l * per;
        const int n = r % H;
        const int k = r / H;
        eW1t[(size_t)l * per + n * 2 * H + k] = f2bf(eW1[i]);
    } else if (i < t1 + t2) {
        const int j = i - t1;
        const int per = H * H;
        const int l = j / per;
        const int r = j - l * per;
        const int n = r % H;
        const int k = r / H;
        nW2t[(size_t)l * per + n * H + k] = f2bf(nW2[j]);
    } else if (i < t1 + 2 * t2) {
        const int j = i - t1 - t2;
        const int per = H * H;
        const int l = j / per;
        const int r = j - l * per;
        const int k = r / H;
        const int o = r % H;
        nW1tc[(size_t)l * H * 2 * H + o * 2 * H + k] =
            f2bf(nW1[(size_t)l * 2 * H * H + k * H + o]);
    }
}

__global__ __launch_bounds__(H) void wcomb_kernel(
    const float* __restrict__ eW2, const float* __restrict__ eb2,
    const float* __restrict__ nW1, unsigned short* __restrict__ W1tc,
    float* __restrict__ cvec) {
    const int l = blockIdx.y;
    const int j = blockIdx.x;   // 0..128
    const int o = threadIdx.x;  // 0..127
    const float* w1 = nW1 + (size_t)l * 2 * H * H + (size_t)H * H;
    const float* row = (j < H) ? (eW2 + (size_t)l * H * H + (size_t)j * H)
                               : (eb2 + (size_t)l * H);
    float s = 0.f;
#pragma unroll 4
    for (int c = 0; c < H; ++c) s = fmaf(row[c], w1[(size_t)c * H + o], s);
    if (j < H)
        W1tc[(size_t)l * H * 2 * H + o * 2 * H + H + j] = f2bf(s);
    else
        cvec[(size_t)l * H + o] = s;
}

// ----------------------- sort-by-dst machinery ----------------------------
__global__ __launch_bounds__(NTHR) void deg_kernel(const int* __restrict__ dst,
                                                   int* __restrict__ deg, int E) {
    const int e = blockIdx.x * NTHR + threadIdx.x;
    if (e < E) atomicAdd(&deg[dst[e]], 1);
}

__global__ __launch_bounds__(1024) void scan1_kernel(
    const int* __restrict__ deg, int* __restrict__ out,
    int* __restrict__ bsum, int N) {
    __shared__ int buf[1024];
    const int t = threadIdx.x;
    const int i = blockIdx.x * 1024 + t;
    const int x = (i < N) ? deg[i] : 0;
    buf[t] = x;
    __syncthreads();
    int v = x;
    for (int off = 1; off < 1024; off <<= 1) {
        const int y = (t >= off) ? buf[t - off] : 0;
        __syncthreads();
        v += y;
        buf[t] = v;
        __syncthreads();
    }
    if (i < N) out[i] = v - x;  // block-local exclusive
    if (t == 1023) bsum[blockIdx.x] = v;
}

__global__ void scan2_kernel(int* __restrict__ bsum, int nb) {
    if (threadIdx.x == 0) {
        int acc = 0;
        for (int i = 0; i < nb; ++i) {
            const int t = bsum[i];
            bsum[i] = acc;
            acc += t;
        }
    }
}

__global__ __launch_bounds__(NTHR) void scan3_kernel(
    int* __restrict__ out, int* __restrict__ cursor,
    const int* __restrict__ bsum, int N, int E) {
    const int i = blockIdx.x * NTHR + threadIdx.x;
    if (i < N) {
        const int v = out[i] + bsum[i >> 10];
        out[i] = v;
        cursor[i] = v;
    } else if (i == N) {
        out[N] = E;
    }
}

__global__ __launch_bounds__(NTHR) void chunk_kernel(
    const int* __restrict__ rowStart, int* __restrict__ chunkLo, int N) {
    const int n = blockIdx.x * NTHR + threadIdx.x;
    if (n < N) atomicMin(&chunkLo[rowStart[n] / CHUNK], n);
}

// srcS holds BYTE offsets into A (src * H * 2)
__global__ __launch_bounds__(NTHR) void scatter_kernel(
    const int* __restrict__ src, const int* __restrict__ dst,
    int* __restrict__ cursor, int* __restrict__ srcS, int E) {
    const int e = blockIdx.x * NTHR + threadIdx.x;
    if (e >= E) return;
    const int pos = atomicAdd(&cursor[dst[e]], 1);
    srcS[pos] = src[e] << 8;  // * 256 bytes per A row
}

// ========================= mega-kernel =====================================
struct MegaArgs {
    const float* nf;
    const float* encW1; const float* encb1;
    const float* encW2; const float* encb2;
    float* h; unsigned short* h_bf;
    unsigned short* A_bf; float* Bf32;
    unsigned short* aggB;
    const int* srcS; const int* rowStart; const int* chunkLo; const int* deg;
    const unsigned short* eW1t;   // [L][128][256]
    const unsigned short* nW1tc;  // [L][128][256]
    const unsigned short* nW2t;   // [L][128][128]
    const float* edge_b1;         // [L][128]
    const float* node_b1; const float* node_b2; const float* cvec;
    const float* decW1; const float* decb1;
    const float* decW2; const float* decb2;
    float* out;
    int N, E, L, numChunks;
};

// fp32 helper for encoder/decoder
template <int K4>
__device__ __forceinline__ void mlp_layer(const float* W, const float* lds,
                                          int ldsStride, int c0, int egBase,
                                          float a0[8], float a1[8]) {
#pragma unroll 2
    for (int k4 = 0; k4 < K4; ++k4) {
        const float w00 = W[(k4 * 4 + 0) * H + c0];
        const float w01 = W[(k4 * 4 + 1) * H + c0];
        const float w02 = W[(k4 * 4 + 2) * H + c0];
        const float w03 = W[(k4 * 4 + 3) * H + c0];
        const float w10 = W[(k4 * 4 + 0) * H + c0 + 64];
        const float w11 = W[(k4 * 4 + 1) * H + c0 + 64];
        const float w12 = W[(k4 * 4 + 2) * H + c0 + 64];
        const float w13 = W[(k4 * 4 + 3) * H + c0 + 64];
#pragma unroll
        for (int e = 0; e < 8; ++e) {
            const float4 x = *reinterpret_cast<const float4*>(
                &lds[(egBase + e) * ldsStride + k4 * 4]);
            a0[e] = fmaf(x.x, w00, a0[e]);
            a0[e] = fmaf(x.y, w01, a0[e]);
            a0[e] = fmaf(x.z, w02, a0[e]);
            a0[e] = fmaf(x.w, w03, a0[e]);
            a1[e] = fmaf(x.x, w10, a1[e]);
            a1[e] = fmaf(x.y, w11, a1[e]);
            a1[e] = fmaf(x.z, w12, a1[e]);
            a1[e] = fmaf(x.w, w13, a1[e]);
        }
    }
}

__device__ void encode_body(int tile, const MegaArgs& a, char* smem) {
    float* xin = (float*)smem;           // 32*16 f32 = 2KB
    float* hm = (float*)(smem + 2048);   // 32*128 f32 = 16KB
    const int t = threadIdx.x;
    const int n0 = tile * TILE;
    const int c0 = t & 63;
    const int eg = t >> 6;
    const int N = a.N;
    __syncthreads();
    for (int i = t; i < TILE * 16; i += NTHR) {
        const int gi = n0 * 16 + i;
        xin[i] = (gi < N * 16) ? a.nf[gi] : 0.f;
    }
    __syncthreads();

    float a0[8], a1[8];
#pragma unroll
    for (int e = 0; e < 8; ++e) { a0[e] = 0.f; a1[e] = 0.f; }
    mlp_layer<4>(a.encW1, xin, 16, c0, eg * 8, a0, a1);
    {
        const float bb0 = a.encb1[c0], bb1 = a.encb1[c0 + 64];
#pragma unroll
        for (int e = 0; e < 8; ++e) {
            hm[(eg * 8 + e) * H + c0] = gelu_fast(a0[e] + bb0);
            hm[(eg * 8 + e) * H + c0 + 64] = gelu_fast(a1[e] + bb1);
        }
    }
    __syncthreads();
#pragma unroll
    for (int e = 0; e < 8; ++e) { a0[e] = 0.f; a1[e] = 0.f; }
    mlp_layer<32>(a.encW2, hm, H, c0, eg * 8, a0, a1);
    const float bb0 = a.encb2[c0], bb1 = a.encb2[c0 + 64];
#pragma unroll
    for (int e = 0; e < 8; ++e) {
        const int n = n0 + eg * 8 + e;
        if (n < N) {
            const float v0 = a0[e] + bb0, v1 = a1[e] + bb1;
            a.h[(size_t)n * H + c0] = v0;
            a.h[(size_t)n * H + c0 + 64] = v1;
            a.h_bf[(size_t)n * H + c0] = f2bf(v0);
            a.h_bf[(size_t)n * H + c0 + 64] = f2bf(v1);
        }
    }
}

__device__ void ab_body(int tile, const MegaArgs& a, char* smem) {
    unsigned short* X = (unsigned short*)smem;  // 64*128 bf16 = 16KB
    const int t = threadIdx.x;
    const int lane = t & 63;
    const int w = t >> 6;
    const int n0 = tile * TE;
    const int l15 = lane & 15;
    const int lq = lane >> 4;
    const int N = a.N;
    const unsigned short* W1t = a.eW1t;  // layer 0
    __syncthreads();

#pragma unroll
    for (int i = 0; i < 4; ++i) {
        const int c = i * NTHR + t;
        const int row = c >> 4;
        const int col8 = c & 15;
        const int n = n0 + row;
        const int4 v = (n < N)
            ? *reinterpret_cast<const int4*>(a.h_bf + (size_t)n * H + col8 * 8)
            : make_int4(0, 0, 0, 0);
        const int byteoff = row * 256 + ((col8 * 16) ^ ((row & 7) << 4));
        *reinterpret_cast<int4*>(reinterpret_cast<char*>(X) + byteoff) = v;
    }

    const int half = w >> 1;  // 0 -> A, 1 -> B
    const int cbase = (w & 1) * 64;
    bf16x8 Bf[4][4];
#pragma unroll
    for (int cg = 0; cg < 4; ++cg) {
        const int col = cbase + cg * 16 + l15;
#pragma unroll
        for (int s = 0; s < 4; ++s)
            Bf[cg][s] = *reinterpret_cast<const bf16x8*>(
                W1t + (size_t)col * 256 + half * 128 + s * 32 + lq * 8);
    }
    __syncthreads();

    f32x4 acc[4][4];
#pragma unroll
    for (int rg = 0; rg < 4; ++rg)
#pragma unroll
        for (int cg = 0; cg < 4; ++cg) acc[rg][cg] = (f32x4)0.f;

#pragma unroll
    for (int s = 0; s < 4; ++s) {
        bf16x8 av[4];
#pragma unroll
        for (int rg = 0; rg < 4; ++rg) {
            const int row = rg * 16 + l15;
            const int byteoff = row * 256 + ((s * 64 + lq * 16) ^ ((row & 7) << 4));
            av[rg] = *reinterpret_cast<const bf16x8*>(
                reinterpret_cast<const char*>(X) + byteoff);
        }
#pragma unroll
        for (int rg = 0; rg < 4; ++rg)
#pragma unroll
            for (int cg = 0; cg < 4; ++cg)
                acc[rg][cg] = __builtin_amdgcn_mfma_f32_16x16x32_bf16(
                    av[rg], Bf[cg][s], acc[rg][cg], 0, 0, 0);
    }

#pragma unroll
    for (int cg = 0; cg < 4; ++cg) {
        const int col = cbase + cg * 16 + l15;
        const float bb = (half == 1) ? a.edge_b1[col] : 0.f;
#pragma unroll
        for (int rg = 0; rg < 4; ++rg) {
#pragma unroll
            for (int r = 0; r < 4; ++r) {
                const int row = rg * 16 + lq * 4 + r;
                const int n = n0 + row;
                if (n < N) {
                    if (half == 0)
                        a.A_bf[(size_t)n * H + col] = f2bf(acc[rg][cg][r]);
                    else
                        a.Bf32[(size_t)n * H + col] = acc[rg][cg][r] + bb;
                }
            }
        }
    }
}

__device__ void gather_chunk(int c, const MegaArgs& a) {
    const int lane = threadIdx.x & 63;
    const int N = a.N;
    int n = a.chunkLo[c];
    if (n >= N) return;  // sentinel: no node starts in this chunk
    const int Wend = (c + 1) * CHUNK;
    const int c2 = lane * 2;
    const char* Abase = (const char*)a.A_bf + (size_t)(lane * 4);
    const int* srcS = a.srcS;
    const int* rowStart = a.rowStart;
    int r0 = rowStart[n];
    while (true) {
        const int r1 = rowStart[n + 1];
        const float2 bv =
            *reinterpret_cast<const float2*>(a.Bf32 + (size_t)n * H + c2);
        float s0 = 0.f, s1 = 0.f;
        int e = r0;
        for (; e + 4 <= r1; e += 4) {
            const int sa = srcS[e];
            const int sb = srcS[e + 1];
            const int sc = srcS[e + 2];
            const int sd = srcS[e + 3];
            const unsigned int va =
                *reinterpret_cast<const unsigned int*>(Abase + sa);
            const unsigned int vb =
                *reinterpret_cast<const unsigned int*>(Abase + sb);
            const unsigned int vc =
                *reinterpret_cast<const unsigned int*>(Abase + sc);
            const unsigned int vd =
                *reinterpret_cast<const unsigned int*>(Abase + sd);
            s0 += gelu_fast(bf2f_lo(va) + bv.x);
            s1 += gelu_fast(bf2f_hi(va) + bv.y);
            s0 += gelu_fast(bf2f_lo(vb) + bv.x);
            s1 += gelu_fast(bf2f_hi(vb) + bv.y);
            s0 += gelu_fast(bf2f_lo(vc) + bv.x);
            s1 += gelu_fast(bf2f_hi(vc) + bv.y);
            s0 += gelu_fast(bf2f_lo(vd) + bv.x);
            s1 += gelu_fast(bf2f_hi(vd) + bv.y);
        }
        for (; e < r1; ++e) {
            const unsigned int av =
                *reinterpret_cast<const unsigned int*>(Abase + srcS[e]);
            s0 += gelu_fast(bf2f_lo(av) + bv.x);
            s1 += gelu_fast(bf2f_hi(av) + bv.y);
        }
        const unsigned int packed =
            (unsigned int)f2bf(s0) | ((unsigned int)f2bf(s1) << 16);
        *reinterpret_cast<unsigned int*>(a.aggB + (size_t)n * H + c2) = packed;
        if (++n >= N) break;
        r0 = r1;
        if (r0 >= Wend) break;
    }
}

__device__ void node_body(int tile, int l, bool prod, const MegaArgs& a,
                          char* smem) {
    unsigned short* X = (unsigned short*)smem;  // 64*256 bf16 = 32KB
    int* degS = (int*)(smem + 32768);           // 64 ints
    const int t = threadIdx.x;
    const int lane = t & 63;
    const int w = t >> 6;
    const int n0 = tile * TE;
    const int l15 = lane & 15;
    const int lq = lane >> 4;
    const int N = a.N;
    const unsigned short* W1tc = a.nW1tc + (size_t)l * 2 * H * H;
    const unsigned short* W2t = a.nW2t + (size_t)l * H * H;
    const float* b1 = a.node_b1 + (size_t)l * H;
    const float* b2 = a.node_b2 + (size_t)l * H;
    const float* cvec = a.cvec + (size_t)l * H;
    const unsigned short* eW1tN = a.eW1t + (size_t)(l + 1) * 2 * H * H;
    const float* eb1N = a.edge_b1 + (size_t)(l + 1) * H;
    __syncthreads();

    if (t < TE) degS[t] = (n0 + t < N) ? a.deg[n0 + t] : 0;
#pragma unroll
    for (int i = 0; i < 8; ++i) {
        const int c = i * NTHR + t;
        const int row = c >> 5;
        const int col8 = c & 31;
        const int n = n0 + row;
        int4 v = make_int4(0, 0, 0, 0);
        if (n < N) {
            const unsigned short* srcp = (col8 < 16) ? a.h_bf : a.aggB;
            v = *reinterpret_cast<const int4*>(srcp + (size_t)n * H +
                                               (col8 & 15) * 8);
        }
        const int byteoff = row * 512 + ((col8 * 16) ^ ((row & 7) << 4));
        *reinterpret_cast<int4*>(reinterpret_cast<char*>(X) + byteoff) = v;
    }

    bf16x8 B1[2][8];
#pragma unroll
    for (int cg = 0; cg < 2; ++cg) {
        const int col = w * 32 + cg * 16 + l15;
#pragma unroll
        for (int s = 0; s < 8; ++s)
            B1[cg][s] = *reinterpret_cast<const bf16x8*>(
                W1tc + (size_t)col * 256 + s * 32 + lq * 8);
    }
    __syncthreads();

    f32x4 acc[4][2];
#pragma unroll
    for (int rg = 0; rg < 4; ++rg)
#pragma unroll
        for (int cg = 0; cg < 2; ++cg) acc[rg][cg] = (f32x4)0.f;

#pragma unroll
    for (int s = 0; s < 8; ++s) {
        bf16x8 av[4];
#pragma unroll
        for (int rg = 0; rg < 4; ++rg) {
            const int row = rg * 16 + l15;
            const int byteoff = row * 512 + ((s * 64 + lq * 16) ^ ((row & 7) << 4));
            av[rg] = *reinterpret_cast<const bf16x8*>(
                reinterpret_cast<const char*>(X) + byteoff);
        }
#pragma unroll
        for (int rg = 0; rg < 4; ++rg)
#pragma unroll
            for (int cg = 0; cg < 2; ++cg)
                acc[rg][cg] = __builtin_amdgcn_mfma_f32_16x16x32_bf16(
                    av[rg], B1[cg][s], acc[rg][cg], 0, 0, 0);
    }
    __syncthreads();

    // L1 epilogue: gelu(acc + b1 + deg*cvec) -> hm (LDS bytes 0..16K)
#pragma unroll
    for (int cg = 0; cg < 2; ++cg) {
        const int col = w * 32 + cg * 16 + l15;
        const float bb = b1[col];
        const float cc = cvec[col];
#pragma unroll
        for (int rg = 0; rg < 4; ++rg) {
#pragma unroll
            for (int r = 0; r < 4; ++r) {
                const int row = rg * 16 + lq * 4 + r;
                const float v =
                    gelu_fast(acc[rg][cg][r] + bb + (float)degS[row] * cc);
                const int byteoff = row * 256 + ((col * 2) ^ ((row & 7) << 4));
                *reinterpret_cast<unsigned short*>(
                    reinterpret_cast<char*>(X) + byteoff) = f2bf(v);
            }
        }
    }

    bf16x8 B2[2][4];
#pragma unroll
    for (int cg = 0; cg < 2; ++cg) {
        const int col = w * 32 + cg * 16 + l15;
#pragma unroll
        for (int s = 0; s < 4; ++s)
            B2[cg][s] = *reinterpret_cast<const bf16x8*>(
                W2t + (size_t)col * 128 + s * 32 + lq * 8);
    }
    __syncthreads();

    f32x4 acc2[4][2];
#pragma unroll
    for (int rg = 0; rg < 4; ++rg)
#pragma unroll
        for (int cg = 0; cg < 2; ++cg) acc2[rg][cg] = (f32x4)0.f;

#pragma unroll
    for (int s = 0; s < 4; ++s) {
        bf16x8 av[4];
#pragma unroll
        for (int rg = 0; rg < 4; ++rg) {
            const int row = rg * 16 + l15;
            const int byteoff = row * 256 + ((s * 64 + lq * 16) ^ ((row & 7) << 4));
            av[rg] = *reinterpret_cast<const bf16x8*>(
                reinterpret_cast<const char*>(X) + byteoff);
        }
#pragma unroll
        for (int rg = 0; rg < 4; ++rg)
#pragma unroll
            for (int cg = 0; cg < 2; ++cg)
                acc2[rg][cg] = __builtin_amdgcn_mfma_f32_16x16x32_bf16(
                    av[rg], B2[cg][s], acc2[rg][cg], 0, 0, 0);
    }

    // residual write: h += update; refresh h_bf; h_new bf16 -> LDS @16KB
#pragma unroll
    for (int cg = 0; cg < 2; ++cg) {
        const int col = w * 32 + cg * 16 + l15;
        const float bb = b2[col];
#pragma unroll
        for (int rg = 0; rg < 4; ++rg) {
#pragma unroll
            for (int r = 0; r < 4; ++r) {
                const int row = rg * 16 + lq * 4 + r;
                const int n = n0 + row;
                if (n < N) {
                    const float hv =
                        a.h[(size_t)n * H + col] + acc2[rg][cg][r] + bb;
                    a.h[(size_t)n * H + col] = hv;
                    const unsigned short hb = f2bf(hv);
                    a.h_bf[(size_t)n * H + col] = hb;
                    if (prod) {
                        const int byteoff =
                            16384 + row * 256 + ((col * 2) ^ ((row & 7) << 4));
                        *reinterpret_cast<unsigned short*>(
                            reinterpret_cast<char*>(X) + byteoff) = hb;
                    }
                } else if (prod) {
                    const int byteoff =
                        16384 + row * 256 + ((col * 2) ^ ((row & 7) << 4));
                    *reinterpret_cast<unsigned short*>(
                        reinterpret_cast<char*>(X) + byteoff) = 0;
                }
            }
        }
    }

    if (prod) {
        bf16x8 B3[2][4], B4[2][4];
#pragma unroll
        for (int cg = 0; cg < 2; ++cg) {
            const int col = w * 32 + cg * 16 + l15;
#pragma unroll
            for (int s = 0; s < 4; ++s) {
                B3[cg][s] = *reinterpret_cast<const bf16x8*>(
                    eW1tN + (size_t)col * 256 + s * 32 + lq * 8);
                B4[cg][s] = *reinterpret_cast<const bf16x8*>(
                    eW1tN + (size_t)col * 256 + 128 + s * 32 + lq * 8);
            }
        }
        __syncthreads();

        f32x4 acc3[4][2], acc4[4][2];
#pragma unroll
        for (int rg = 0; rg < 4; ++rg)
#pragma unroll
            for (int cg = 0; cg < 2; ++cg) {
                acc3[rg][cg] = (f32x4)0.f;
                acc4[rg][cg] = (f32x4)0.f;
            }

#pragma unroll
        for (int s = 0; s < 4; ++s) {
            bf16x8 av[4];
#pragma unroll
            for (int rg = 0; rg < 4; ++rg) {
                const int row = rg * 16 + l15;
                const int byteoff =
                    16384 + row * 256 + ((s * 64 + lq * 16) ^ ((row & 7) << 4));
                av[rg] = *reinterpret_cast<const bf16x8*>(
                    reinterpret_cast<const char*>(X) + byteoff);
            }
#pragma unroll
            for (int rg = 0; rg < 4; ++rg)
#pragma unroll
                for (int cg = 0; cg < 2; ++cg) {
                    acc3[rg][cg] = __builtin_amdgcn_mfma_f32_16x16x32_bf16(
                        av[rg], B3[cg][s], acc3[rg][cg], 0, 0, 0);
                    acc4[rg][cg] = __builtin_amdgcn_mfma_f32_16x16x32_bf16(
                        av[rg], B4[cg][s], acc4[rg][cg], 0, 0, 0);
                }
        }

#pragma unroll
        for (int cg = 0; cg < 2; ++cg) {
            const int col = w * 32 + cg * 16 + l15;
            const float bb = eb1N[col];
#pragma unroll
            for (int rg = 0; rg < 4; ++rg) {
#pragma unroll
                for (int r = 0; r < 4; ++r) {
                    const int row = rg * 16 + lq * 4 + r;
                    const int n = n0 + row;
                    if (n < N) {
                        a.A_bf[(size_t)n * H + col] = f2bf(acc3[rg][cg][r]);
                        a.Bf32[(size_t)n * H + col] = acc4[rg][cg][r] + bb;
                    }
                }
            }
        }
    }
}

__device__ void dec_body(int tile, const MegaArgs& a, char* smem) {
    float* xin = (float*)smem;            // 32*128 f32 = 16KB
    float* hm = (float*)(smem + 16384);   // 32*132 f32 = 16.9KB
    const int t = threadIdx.x;
    const int n0 = tile * TILE;
    const int c0 = t & 63;
    const int eg = t >> 6;
    const int N = a.N;
    __syncthreads();
    {
        const int col = t & 127;
        for (int e = t >> 7; e < TILE; e += 2) {
            const int n = n0 + e;
            xin[e * H + col] = (n < N) ? a.h[(size_t)n * H + col] : 0.f;
        }
    }
    __syncthreads();

    float a0[8], a1[8];
#pragma unroll
    for (int e = 0; e < 8; ++e) { a0[e] = 0.f; a1[e] = 0.f; }
    mlp_layer<32>(a.decW1, xin, H, c0, eg * 8, a0, a1);
    {
        const float bb0 = a.decb1[c0], bb1 = a.decb1[c0 + 64];
#pragma unroll
        for (int e = 0; e < 8; ++e) {
            hm[(eg * 8 + e) * 132 + c0] = gelu_fast(a0[e] + bb0);
            hm[(eg * 8 + e) * 132 + c0 + 64] = gelu_fast(a1[e] + bb1);
        }
    }
    __syncthreads();
    {
        const int e = t >> 3;
        const int o = t & 7;
        const int n = n0 + e;
        float acc = a.decb2[o];
#pragma unroll 4
        for (int k = 0; k < H; ++k)
            acc = fmaf(hm[e * 132 + k], a.decW2[k * 8 + o], acc);
        if (n < N) a.out[n * 8 + o] = acc;
    }
}

__global__ __launch_bounds__(NTHR, 4) void mega_kernel(MegaArgs a) {
    cg::grid_group grid = cg::this_grid();
    __shared__ __align__(16) char smem[33792];
    const int encTiles = (a.N + TILE - 1) / TILE;
    const int nodeTiles = (a.N + TE - 1) / TE;

    for (int tile = blockIdx.x; tile < encTiles; tile += gridDim.x)
        encode_body(tile, a, smem);
    grid.sync();

    for (int tile = blockIdx.x; tile < nodeTiles; tile += gridDim.x)
        ab_body(tile, a, smem);
    grid.sync();

    for (int l = 0; l < a.L; ++l) {
        const int totW = gridDim.x * 4;
        for (int c = blockIdx.x * 4 + (threadIdx.x >> 6); c < a.numChunks;
             c += totW)
            gather_chunk(c, a);
        grid.sync();

        const bool prod = (l + 1 < a.L);
        for (int tile = blockIdx.x; tile < nodeTiles; tile += gridDim.x)
            node_body(tile, l, prod, a, smem);
        grid.sync();
    }

    for (int tile = blockIdx.x; tile < encTiles; tile += gridDim.x)
        dec_body(tile, a, smem);
}

extern "C" void kernel_launch(void* const* d_in, const int* in_sizes, int n_in,
                              void* d_out, int out_size, void* d_ws,
                              size_t ws_size, hipStream_t stream) {
    (void)n_in; (void)out_size; (void)ws_size;
    const float* nf      = (const float*)d_in[0];
    const int*   ei      = (const int*)d_in[1];
    const float* enc_W1  = (const float*)d_in[2];
    const float* enc_b1  = (const float*)d_in[3];
    const float* enc_W2  = (const float*)d_in[4];
    const float* enc_b2  = (const float*)d_in[5];
    const float* edge_W1 = (const float*)d_in[6];
    const float* edge_b1 = (const float*)d_in[7];
    const float* edge_W2 = (const float*)d_in[8];
    const float* edge_b2 = (const float*)d_in[9];
    const float* node_W1 = (const float*)d_in[10];
    const float* node_b1 = (const float*)d_in[11];
    const float* node_W2 = (const float*)d_in[12];
    const float* node_b2 = (const float*)d_in[13];
    const float* dec_W1  = (const float*)d_in[14];
    const float* dec_b1  = (const float*)d_in[15];
    const float* dec_W2  = (const float*)d_in[16];
    const float* dec_b2  = (const float*)d_in[17];

    const int N = in_sizes[0] / 16;
    const int E = in_sizes[1] / 2;
    const int L = in_sizes[7] / H;  // edge_b1 is [L,H]
    const int numChunks = E / CHUNK + 1;

    // ---------------- workspace layout ----------------
    char* ws = (char*)d_ws;
    float* h    = (float*)ws;                    ws += (size_t)N * H * 4;
    float* Bf32 = (float*)ws;                    ws += (size_t)N * H * 4;
    unsigned short* h_bf = (unsigned short*)ws;  ws += (size_t)N * H * 2;
    unsigned short* A_bf = (unsigned short*)ws;  ws += (size_t)N * H * 2;
    unsigned short* aggB = (unsigned short*)ws;  ws += (size_t)N * H * 2;
    int* srcS     = (int*)ws;                    ws += (size_t)E * 4;
    int* deg      = (int*)ws;                    ws += (size_t)N * 4;
    int* rowStart = (int*)ws;                    ws += (size_t)(N + 1) * 4;
    int* cursor   = (int*)ws;                    ws += (size_t)N * 4;
    int* bsum     = (int*)ws;                    ws += (size_t)256 * 4;
    int* chunkLo  = (int*)ws;                    ws += (size_t)numChunks * 4;
    unsigned short* eW1t = (unsigned short*)ws;  ws += (size_t)L * 2 * H * H * 2;
    unsigned short* nW1tc = (unsigned short*)ws; ws += (size_t)L * 2 * H * H * 2;
    unsigned short* nW2t = (unsigned short*)ws;  ws += (size_t)L * H * H * 2;
    float* cvec   = (float*)ws;                  ws += (size_t)L * H * 4;

    const int* srcArr = ei;
    const int* dstArr = ei + E;

    // ---- weight prep (tiny) ----
    {
        const int t1 = L * 2 * H * H, t2 = L * H * H;
        prep_kernel<<<(t1 + 2 * t2 + NTHR - 1) / NTHR, NTHR, 0, stream>>>(
            edge_W1, node_W2, node_W1, eW1t, nW2t, nW1tc, t1, t2);
        wcomb_kernel<<<dim3(H + 1, L), H, 0, stream>>>(edge_W2, edge_b2,
                                                       node_W1, nW1tc, cvec);
    }

    // ---- sort edges by dst (hist + multiblock scan + scatter) ----
    hipMemsetAsync(deg, 0, (size_t)N * 4, stream);
    deg_kernel<<<(E + NTHR - 1) / NTHR, NTHR, 0, stream>>>(dstArr, deg, E);
    const int nScanB = (N + 1023) / 1024;
    scan1_kernel<<<nScanB, 1024, 0, stream>>>(deg, rowStart, bsum, N);
    scan2_kernel<<<1, 64, 0, stream>>>(bsum, nScanB);
    scan3_kernel<<<(N + 1 + NTHR - 1) / NTHR, NTHR, 0, stream>>>(
        rowStart, cursor, bsum, N, E);
    hipMemsetAsync(chunkLo, 0x7f, (size_t)numChunks * 4, stream);
    chunk_kernel<<<(N + NTHR - 1) / NTHR, NTHR, 0, stream>>>(rowStart, chunkLo, N);
    scatter_kernel<<<(E + NTHR - 1) / NTHR, NTHR, 0, stream>>>(srcArr, dstArr,
                                                               cursor, srcS, E);

    // ---- cooperative mega-kernel: enc -> ab -> [gather->node]x4 -> dec ----
    MegaArgs margs;
    margs.nf = nf;
    margs.encW1 = enc_W1; margs.encb1 = enc_b1;
    margs.encW2 = enc_W2; margs.encb2 = enc_b2;
    margs.h = h; margs.h_bf = h_bf;
    margs.A_bf = A_bf; margs.Bf32 = Bf32;
    margs.aggB = aggB;
    margs.srcS = srcS; margs.rowStart = rowStart;
    margs.chunkLo = chunkLo; margs.deg = deg;
    margs.eW1t = eW1t; margs.nW1tc = nW1tc; margs.nW2t = nW2t;
    margs.edge_b1 = edge_b1;
    margs.node_b1 = node_b1; margs.node_b2 = node_b2; margs.cvec = cvec;
    margs.decW1 = dec_W1; margs.decb1 = dec_b1;
    margs.decW2 = dec_W2; margs.decb2 = dec_b2;
    margs.out = (float*)d_out;
    margs.N = N; margs.E = E; margs.L = L; margs.numChunks = numChunks;

    int blocksPerCU = 0;
    hipOccupancyMaxActiveBlocksPerMultiprocessor(&blocksPerCU, mega_kernel,
                                                 NTHR, 0);
    if (blocksPerCU < 1) blocksPerCU = 1;
    if (blocksPerCU > 8) blocksPerCU = 8;
    const int grid = blocksPerCU * 256;  // 256 CUs on MI355X

    void* kargs[] = {(void*)&margs};
    hipLaunchCooperativeKernel((const void*)mega_kernel, dim3(grid),
                               dim3(NTHR), kargs, 0, stream);
}

// Round 10
// 728.052 us; speedup vs baseline: 2.4922x; 2.4922x over previous
//
#include <hip/hip_runtime.h>
#include <math.h>

// FieldlineGraphForecaster round 9: r7 structure (best: 694us).
// r8 lesson: cooperative grid.sync costs >100us/sync on MI355X (load
// imbalance + non-coherent per-XCD L2 flush; FETCH +340MB) -- dead end.
// This round: gather column-split (2 waves/chunk, 1 col/lane, 8x unroll;
// bit-identical order) + chunk/scatter merged + chunkLo memset folded.

constexpr int H = 128;
constexpr int NTHR = 256;
constexpr int TE = 64;    // rows per MFMA tile
constexpr int TILE = 32;  // rows per fp32 (enc/dec) tile
constexpr int CHUNK = 16; // sorted edges per chunk

using bf16x8 = __attribute__((ext_vector_type(8))) short;
using f32x4  = __attribute__((ext_vector_type(4))) float;

// Branchless GELU: A&S 7.1.26 erf (5-term), |eps|<=1.5e-7. DO NOT downgrade:
// 3-term (2.5e-5) fails the harness threshold (r6: absmax 80 > 78).
__device__ __forceinline__ float gelu_fast(float x) {
    const float u = fabsf(x) * 0.70710678118654752440f;
    const float t = __builtin_amdgcn_rcpf(fmaf(0.3275911f, u, 1.f));
    float p = fmaf(1.061405429f, t, -1.453152027f);
    p = fmaf(p, t, 1.421413741f);
    p = fmaf(p, t, -0.284496736f);
    p = fmaf(p, t, 0.254829592f);
    p = p * t;
    const float e = __expf(-u * u);
    float er = fmaf(-p, e, 1.f);  // erf(|x|/sqrt2)
    er = copysignf(er, x);
    return 0.5f * x * (1.f + er);
}

__device__ __forceinline__ unsigned short f2bf(float f) {
    unsigned int u = __builtin_bit_cast(unsigned int, f);
    u = (u + 0x7fffu + ((u >> 16) & 1u)) >> 16;
    return (unsigned short)u;
}

__device__ __forceinline__ float bf2f(unsigned short v) {
    return __builtin_bit_cast(float, (unsigned int)v << 16);
}

// ---- merged weight prep: eW1t, nW2t, nW1tc(top) in one kernel ------------
__global__ __launch_bounds__(NTHR) void prep_kernel(
    const float* __restrict__ eW1, const float* __restrict__ nW2,
    const float* __restrict__ nW1, unsigned short* __restrict__ eW1t,
    unsigned short* __restrict__ nW2t, unsigned short* __restrict__ nW1tc,
    int t1, int t2) {
    const int i = blockIdx.x * NTHR + threadIdx.x;
    if (i < t1) {
        const int per = 2 * H * H;
        const int l = i / per;
        const int r = i - l * per;
        const int n = r % H;
        const int k = r / H;
        eW1t[(size_t)l * per + n * 2 * H + k] = f2bf(eW1[i]);
    } else if (i < t1 + t2) {
        const int j = i - t1;
        const int per = H * H;
        const int l = j / per;
        const int r = j - l * per;
        const int n = r % H;
        const int k = r / H;
        nW2t[(size_t)l * per + n * H + k] = f2bf(nW2[j]);
    } else if (i < t1 + 2 * t2) {
        const int j = i - t1 - t2;
        const int per = H * H;
        const int l = j / per;
        const int r = j - l * per;
        const int k = r / H;
        const int o = r % H;
        nW1tc[(size_t)l * H * 2 * H + o * 2 * H + k] =
            f2bf(nW1[(size_t)l * 2 * H * H + k * H + o]);
    }
}

// ---- Wcomb[j][o] = sum_c eW2[j][c]*nW1[128+c][o] -> nW1tc bottom half; and
//      cvec[o] = sum_c eb2[c]*nW1[128+c][o] (j==128 block).
__global__ __launch_bounds__(H) void wcomb_kernel(
    const float* __restrict__ eW2, const float* __restrict__ eb2,
    const float* __restrict__ nW1, unsigned short* __restrict__ W1tc,
    float* __restrict__ cvec) {
    const int l = blockIdx.y;
    const int j = blockIdx.x;   // 0..128
    const int o = threadIdx.x;  // 0..127
    const float* w1 = nW1 + (size_t)l * 2 * H * H + (size_t)H * H;
    const float* row = (j < H) ? (eW2 + (size_t)l * H * H + (size_t)j * H)
                               : (eb2 + (size_t)l * H);
    float s = 0.f;
#pragma unroll 4
    for (int c = 0; c < H; ++c) s = fmaf(row[c], w1[(size_t)c * H + o], s);
    if (j < H)
        W1tc[(size_t)l * H * 2 * H + o * 2 * H + H + j] = f2bf(s);
    else
        cvec[(size_t)l * H + o] = s;
}

// ----------------------- sort-by-dst machinery ----------------------------
__global__ __launch_bounds__(NTHR) void deg_kernel(const int* __restrict__ dst,
                                                   int* __restrict__ deg, int E) {
    const int e = blockIdx.x * NTHR + threadIdx.x;
    if (e < E) atomicAdd(&deg[dst[e]], 1);
}

__global__ __launch_bounds__(1024) void scan1_kernel(
    const int* __restrict__ deg, int* __restrict__ out,
    int* __restrict__ bsum, int N) {
    __shared__ int buf[1024];
    const int t = threadIdx.x;
    const int i = blockIdx.x * 1024 + t;
    const int x = (i < N) ? deg[i] : 0;
    buf[t] = x;
    __syncthreads();
    int v = x;
    for (int off = 1; off < 1024; off <<= 1) {
        const int y = (t >= off) ? buf[t - off] : 0;
        __syncthreads();
        v += y;
        buf[t] = v;
        __syncthreads();
    }
    if (i < N) out[i] = v - x;  // block-local exclusive
    if (t == 1023) bsum[blockIdx.x] = v;
}

__global__ void scan2_kernel(int* __restrict__ bsum, int nb) {
    if (threadIdx.x == 0) {
        int acc = 0;
        for (int i = 0; i < nb; ++i) {
            const int t = bsum[i];
            bsum[i] = acc;
            acc += t;
        }
    }
}

// also initializes chunkLo sentinel (saves a memset dispatch)
__global__ __launch_bounds__(NTHR) void scan3_kernel(
    int* __restrict__ out, int* __restrict__ cursor,
    const int* __restrict__ bsum, int* __restrict__ chunkLo, int N, int E,
    int numChunks) {
    const int i = blockIdx.x * NTHR + threadIdx.x;
    if (i < N) {
        const int v = out[i] + bsum[i >> 10];
        out[i] = v;
        cursor[i] = v;
    } else if (i == N) {
        out[N] = E;
    }
    if (i < numChunks) chunkLo[i] = 0x7fffffff;
}

// merged: chunkLo atomicMin + dst-sorted scatter (both depend only on scan3)
// srcS holds BYTE offsets into A (src * H * 2)
__global__ __launch_bounds__(NTHR) void finalize_kernel(
    const int* __restrict__ rowStart, int* __restrict__ chunkLo,
    const int* __restrict__ src, const int* __restrict__ dst,
    int* __restrict__ cursor, int* __restrict__ srcS, int N, int E) {
    const int i = blockIdx.x * NTHR + threadIdx.x;
    if (i < N) atomicMin(&chunkLo[rowStart[i] / CHUNK], i);
    if (i < E) {
        const int pos = atomicAdd(&cursor[dst[i]], 1);
        srcS[pos] = src[i] << 8;  // * 256 bytes per A row
    }
}

// ---- A/B kernel (layer 0 only): A = h@W1_top (bf16), B = h@W1_bot+b1 -----
__global__ __launch_bounds__(NTHR) void ab_kernel(
    const unsigned short* __restrict__ h_bf,
    const unsigned short* __restrict__ W1t,  // [128 cols][256 k]
    const float* __restrict__ b1, unsigned short* __restrict__ A,
    float* __restrict__ Bout, int N) {
    __shared__ __align__(16) unsigned short X[TE * H];  // 16KB
    const int t = threadIdx.x;
    const int lane = t & 63;
    const int w = t >> 6;
    const int n0 = blockIdx.x * TE;
    const int l15 = lane & 15;
    const int lq = lane >> 4;

#pragma unroll
    for (int i = 0; i < 4; ++i) {
        const int c = i * NTHR + t;
        const int row = c >> 4;
        const int col8 = c & 15;
        const int n = n0 + row;
        const int4 v = (n < N)
            ? *reinterpret_cast<const int4*>(h_bf + (size_t)n * H + col8 * 8)
            : make_int4(0, 0, 0, 0);
        const int byteoff = row * 256 + ((col8 * 16) ^ ((row & 7) << 4));
        *reinterpret_cast<int4*>(reinterpret_cast<char*>(X) + byteoff) = v;
    }

    const int half = w >> 1;  // 0 -> A, 1 -> B
    const int cbase = (w & 1) * 64;
    bf16x8 Bf[4][4];
#pragma unroll
    for (int cg = 0; cg < 4; ++cg) {
        const int col = cbase + cg * 16 + l15;
#pragma unroll
        for (int s = 0; s < 4; ++s)
            Bf[cg][s] = *reinterpret_cast<const bf16x8*>(
                W1t + (size_t)col * 256 + half * 128 + s * 32 + lq * 8);
    }
    __syncthreads();

    f32x4 acc[4][4];
#pragma unroll
    for (int rg = 0; rg < 4; ++rg)
#pragma unroll
        for (int cg = 0; cg < 4; ++cg) acc[rg][cg] = (f32x4)0.f;

#pragma unroll
    for (int s = 0; s < 4; ++s) {
        bf16x8 a[4];
#pragma unroll
        for (int rg = 0; rg < 4; ++rg) {
            const int row = rg * 16 + l15;
            const int byteoff = row * 256 + ((s * 64 + lq * 16) ^ ((row & 7) << 4));
            a[rg] = *reinterpret_cast<const bf16x8*>(
                reinterpret_cast<const char*>(X) + byteoff);
        }
#pragma unroll
        for (int rg = 0; rg < 4; ++rg)
#pragma unroll
            for (int cg = 0; cg < 4; ++cg)
                acc[rg][cg] = __builtin_amdgcn_mfma_f32_16x16x32_bf16(
                    a[rg], Bf[cg][s], acc[rg][cg], 0, 0, 0);
    }

#pragma unroll
    for (int cg = 0; cg < 4; ++cg) {
        const int col = cbase + cg * 16 + l15;
        const float bb = (half == 1) ? b1[col] : 0.f;
#pragma unroll
        for (int rg = 0; rg < 4; ++rg) {
#pragma unroll
            for (int r = 0; r < 4; ++r) {
                const int row = rg * 16 + lq * 4 + r;
                const int n = n0 + row;
                if (n < N) {
                    if (half == 0)
                        A[(size_t)n * H + col] = f2bf(acc[rg][cg][r]);
                    else
                        Bout[(size_t)n * H + col] = acc[rg][cg][r] + bb;
                }
            }
        }
    }
}

// ---- edge gather: column-split waves (1 col/lane), 8x edge unroll --------
// Job j = chunk (j>>1), column half (j&1). Per-column edge order identical
// to previous rounds -> bit-identical results.
__global__ __launch_bounds__(NTHR) void edge_gather_kernel(
    const unsigned short* __restrict__ A, const float* __restrict__ B,
    const int* __restrict__ srcS, const int* __restrict__ rowStart,  // N+1
    const int* __restrict__ chunkLo, unsigned short* __restrict__ aggB,
    int N, int E) {
    const int lane = threadIdx.x & 63;
    const int job = blockIdx.x * 4 + (threadIdx.x >> 6);
    const int nJobs = (E / CHUNK + 1) * 2;
    if (job >= nJobs) return;
    const int c = job >> 1;
    const int col = (job & 1) * 64 + lane;
    int n = chunkLo[c];
    if (n >= N) return;  // sentinel: no node starts in this chunk
    const int Wend = (c + 1) * CHUNK;
    const char* Abase = (const char*)A + (size_t)(col * 2);
    int r0 = rowStart[n];
    while (true) {
        const int r1 = rowStart[n + 1];
        const float bv = B[(size_t)n * H + col];
        float s = 0.f;
        int e = r0;
        for (; e + 8 <= r1; e += 8) {
            unsigned short v0 = *reinterpret_cast<const unsigned short*>(Abase + srcS[e]);
            unsigned short v1 = *reinterpret_cast<const unsigned short*>(Abase + srcS[e + 1]);
            unsigned short v2 = *reinterpret_cast<const unsigned short*>(Abase + srcS[e + 2]);
            unsigned short v3 = *reinterpret_cast<const unsigned short*>(Abase + srcS[e + 3]);
            unsigned short v4 = *reinterpret_cast<const unsigned short*>(Abase + srcS[e + 4]);
            unsigned short v5 = *reinterpret_cast<const unsigned short*>(Abase + srcS[e + 5]);
            unsigned short v6 = *reinterpret_cast<const unsigned short*>(Abase + srcS[e + 6]);
            unsigned short v7 = *reinterpret_cast<const unsigned short*>(Abase + srcS[e + 7]);
            s += gelu_fast(bf2f(v0) + bv);
            s += gelu_fast(bf2f(v1) + bv);
            s += gelu_fast(bf2f(v2) + bv);
            s += gelu_fast(bf2f(v3) + bv);
            s += gelu_fast(bf2f(v4) + bv);
            s += gelu_fast(bf2f(v5) + bv);
            s += gelu_fast(bf2f(v6) + bv);
            s += gelu_fast(bf2f(v7) + bv);
        }
        for (; e + 4 <= r1; e += 4) {
            unsigned short v0 = *reinterpret_cast<const unsigned short*>(Abase + srcS[e]);
            unsigned short v1 = *reinterpret_cast<const unsigned short*>(Abase + srcS[e + 1]);
            unsigned short v2 = *reinterpret_cast<const unsigned short*>(Abase + srcS[e + 2]);
            unsigned short v3 = *reinterpret_cast<const unsigned short*>(Abase + srcS[e + 3]);
            s += gelu_fast(bf2f(v0) + bv);
            s += gelu_fast(bf2f(v1) + bv);
            s += gelu_fast(bf2f(v2) + bv);
            s += gelu_fast(bf2f(v3) + bv);
        }
        for (; e < r1; ++e) {
            unsigned short v0 = *reinterpret_cast<const unsigned short*>(Abase + srcS[e]);
            s += gelu_fast(bf2f(v0) + bv);
        }
        aggB[(size_t)n * H + col] = f2bf(s);
        if (++n >= N) break;
        r0 = r1;
        if (r0 >= Wend) break;
    }
}

// ---- fused node update (+ next-layer A/B production) ---------------------
// h += MLP([h | aggB]; W1'=[nW1_top;Wcomb], b1'=b1+deg*cvec); refresh h_bf.
// If PROD: A_out = h_new@eW1_top(next), B_out = h_new@eW1_bot(next)+eb1(next).
template <bool PROD>
__global__ __launch_bounds__(NTHR) void node_fused_kernel(
    float* __restrict__ h, unsigned short* __restrict__ h_bf,
    const unsigned short* __restrict__ aggB, const int* __restrict__ deg,
    const unsigned short* __restrict__ W1tc, const float* __restrict__ b1,
    const float* __restrict__ cvec, const unsigned short* __restrict__ W2t,
    const float* __restrict__ b2, const unsigned short* __restrict__ eW1tN,
    const float* __restrict__ eb1N, unsigned short* __restrict__ A_out,
    float* __restrict__ B_out, int N) {
    __shared__ __align__(16) unsigned short X[TE * 256];  // 32KB
    __shared__ int degS[TE];
    const int t = threadIdx.x;
    const int lane = t & 63;
    const int w = t >> 6;
    const int n0 = blockIdx.x * TE;
    const int l15 = lane & 15;
    const int lq = lane >> 4;

    if (t < TE) degS[t] = (n0 + t < N) ? deg[n0 + t] : 0;
#pragma unroll
    for (int i = 0; i < 8; ++i) {
        const int c = i * NTHR + t;
        const int row = c >> 5;
        const int col8 = c & 31;
        const int n = n0 + row;
        int4 v = make_int4(0, 0, 0, 0);
        if (n < N) {
            const unsigned short* srcp = (col8 < 16) ? h_bf : aggB;
            v = *reinterpret_cast<const int4*>(srcp + (size_t)n * H +
                                               (col8 & 15) * 8);
        }
        const int byteoff = row * 512 + ((col8 * 16) ^ ((row & 7) << 4));
        *reinterpret_cast<int4*>(reinterpret_cast<char*>(X) + byteoff) = v;
    }

    bf16x8 B1[2][8];
#pragma unroll
    for (int cg = 0; cg < 2; ++cg) {
        const int col = w * 32 + cg * 16 + l15;
#pragma unroll
        for (int s = 0; s < 8; ++s)
            B1[cg][s] = *reinterpret_cast<const bf16x8*>(
                W1tc + (size_t)col * 256 + s * 32 + lq * 8);
    }
    __syncthreads();

    f32x4 acc[4][2];
#pragma unroll
    for (int rg = 0; rg < 4; ++rg)
#pragma unroll
        for (int cg = 0; cg < 2; ++cg) acc[rg][cg] = (f32x4)0.f;

#pragma unroll
    for (int s = 0; s < 8; ++s) {
        bf16x8 a[4];
#pragma unroll
        for (int rg = 0; rg < 4; ++rg) {
            const int row = rg * 16 + l15;
            const int byteoff = row * 512 + ((s * 64 + lq * 16) ^ ((row & 7) << 4));
            a[rg] = *reinterpret_cast<const bf16x8*>(
                reinterpret_cast<const char*>(X) + byteoff);
        }
#pragma unroll
        for (int rg = 0; rg < 4; ++rg)
#pragma unroll
            for (int cg = 0; cg < 2; ++cg)
                acc[rg][cg] = __builtin_amdgcn_mfma_f32_16x16x32_bf16(
                    a[rg], B1[cg][s], acc[rg][cg], 0, 0, 0);
    }
    __syncthreads();

    // L1 epilogue: gelu(acc + b1 + deg*cvec) -> hm (LDS bytes 0..16K)
#pragma unroll
    for (int cg = 0; cg < 2; ++cg) {
        const int col = w * 32 + cg * 16 + l15;
        const float bb = b1[col];
        const float cc = cvec[col];
#pragma unroll
        for (int rg = 0; rg < 4; ++rg) {
#pragma unroll
            for (int r = 0; r < 4; ++r) {
                const int row = rg * 16 + lq * 4 + r;
                const float v =
                    gelu_fast(acc[rg][cg][r] + bb + (float)degS[row] * cc);
                const int byteoff = row * 256 + ((col * 2) ^ ((row & 7) << 4));
                *reinterpret_cast<unsigned short*>(
                    reinterpret_cast<char*>(X) + byteoff) = f2bf(v);
            }
        }
    }

    bf16x8 B2[2][4];
#pragma unroll
    for (int cg = 0; cg < 2; ++cg) {
        const int col = w * 32 + cg * 16 + l15;
#pragma unroll
        for (int s = 0; s < 4; ++s)
            B2[cg][s] = *reinterpret_cast<const bf16x8*>(
                W2t + (size_t)col * 128 + s * 32 + lq * 8);
    }
    __syncthreads();

    f32x4 acc2[4][2];
#pragma unroll
    for (int rg = 0; rg < 4; ++rg)
#pragma unroll
        for (int cg = 0; cg < 2; ++cg) acc2[rg][cg] = (f32x4)0.f;

#pragma unroll
    for (int s = 0; s < 4; ++s) {
        bf16x8 a[4];
#pragma unroll
        for (int rg = 0; rg < 4; ++rg) {
            const int row = rg * 16 + l15;
            const int byteoff = row * 256 + ((s * 64 + lq * 16) ^ ((row & 7) << 4));
            a[rg] = *reinterpret_cast<const bf16x8*>(
                reinterpret_cast<const char*>(X) + byteoff);
        }
#pragma unroll
        for (int rg = 0; rg < 4; ++rg)
#pragma unroll
            for (int cg = 0; cg < 2; ++cg)
                acc2[rg][cg] = __builtin_amdgcn_mfma_f32_16x16x32_bf16(
                    a[rg], B2[cg][s], acc2[rg][cg], 0, 0, 0);
    }

    // residual write: h += update; refresh h_bf; h_new bf16 -> LDS @16KB
#pragma unroll
    for (int cg = 0; cg < 2; ++cg) {
        const int col = w * 32 + cg * 16 + l15;
        const float bb = b2[col];
#pragma unroll
        for (int rg = 0; rg < 4; ++rg) {
#pragma unroll
            for (int r = 0; r < 4; ++r) {
                const int row = rg * 16 + lq * 4 + r;
                const int n = n0 + row;
                if (n < N) {
                    const float hv = h[(size_t)n * H + col] + acc2[rg][cg][r] + bb;
                    h[(size_t)n * H + col] = hv;
                    const unsigned short hb = f2bf(hv);
                    h_bf[(size_t)n * H + col] = hb;
                    if (PROD) {
                        const int byteoff =
                            16384 + row * 256 + ((col * 2) ^ ((row & 7) << 4));
                        *reinterpret_cast<unsigned short*>(
                            reinterpret_cast<char*>(X) + byteoff) = hb;
                    }
                } else if (PROD) {
                    const int byteoff =
                        16384 + row * 256 + ((col * 2) ^ ((row & 7) << 4));
                    *reinterpret_cast<unsigned short*>(
                        reinterpret_cast<char*>(X) + byteoff) = 0;
                }
            }
        }
    }

    if (PROD) {
        bf16x8 B3[2][4], B4[2][4];
#pragma unroll
        for (int cg = 0; cg < 2; ++cg) {
            const int col = w * 32 + cg * 16 + l15;
#pragma unroll
            for (int s = 0; s < 4; ++s) {
                B3[cg][s] = *reinterpret_cast<const bf16x8*>(
                    eW1tN + (size_t)col * 256 + s * 32 + lq * 8);
                B4[cg][s] = *reinterpret_cast<const bf16x8*>(
                    eW1tN + (size_t)col * 256 + 128 + s * 32 + lq * 8);
            }
        }
        __syncthreads();

        f32x4 acc3[4][2], acc4[4][2];
#pragma unroll
        for (int rg = 0; rg < 4; ++rg)
#pragma unroll
            for (int cg = 0; cg < 2; ++cg) {
                acc3[rg][cg] = (f32x4)0.f;
                acc4[rg][cg] = (f32x4)0.f;
            }

#pragma unroll
        for (int s = 0; s < 4; ++s) {
            bf16x8 a[4];
#pragma unroll
            for (int rg = 0; rg < 4; ++rg) {
                const int row = rg * 16 + l15;
                const int byteoff =
                    16384 + row * 256 + ((s * 64 + lq * 16) ^ ((row & 7) << 4));
                a[rg] = *reinterpret_cast<const bf16x8*>(
                    reinterpret_cast<const char*>(X) + byteoff);
            }
#pragma unroll
            for (int rg = 0; rg < 4; ++rg)
#pragma unroll
                for (int cg = 0; cg < 2; ++cg) {
                    acc3[rg][cg] = __builtin_amdgcn_mfma_f32_16x16x32_bf16(
                        a[rg], B3[cg][s], acc3[rg][cg], 0, 0, 0);
                    acc4[rg][cg] = __builtin_amdgcn_mfma_f32_16x16x32_bf16(
                        a[rg], B4[cg][s], acc4[rg][cg], 0, 0, 0);
                }
        }

#pragma unroll
        for (int cg = 0; cg < 2; ++cg) {
            const int col = w * 32 + cg * 16 + l15;
            const float bb = eb1N[col];
#pragma unroll
            for (int rg = 0; rg < 4; ++rg) {
#pragma unroll
                for (int r = 0; r < 4; ++r) {
                    const int row = rg * 16 + lq * 4 + r;
                    const int n = n0 + row;
                    if (n < N) {
                        A_out[(size_t)n * H + col] = f2bf(acc3[rg][cg][r]);
                        B_out[(size_t)n * H + col] = acc4[rg][cg][r] + bb;
                    }
                }
            }
        }
    }
}

// ---------------- fp32 helper for encoder/decoder -------------------------
template <int K4>
__device__ __forceinline__ void mlp_layer(const float* __restrict__ W,
                                          const float* lds, int ldsStride,
                                          int c0, int egBase,
                                          float a0[8], float a1[8]) {
#pragma unroll 2
    for (int k4 = 0; k4 < K4; ++k4) {
        const float w00 = W[(k4 * 4 + 0) * H + c0];
        const float w01 = W[(k4 * 4 + 1) * H + c0];
        const float w02 = W[(k4 * 4 + 2) * H + c0];
        const float w03 = W[(k4 * 4 + 3) * H + c0];
        const float w10 = W[(k4 * 4 + 0) * H + c0 + 64];
        const float w11 = W[(k4 * 4 + 1) * H + c0 + 64];
        const float w12 = W[(k4 * 4 + 2) * H + c0 + 64];
        const float w13 = W[(k4 * 4 + 3) * H + c0 + 64];
#pragma unroll
        for (int e = 0; e < 8; ++e) {
            const float4 x = *reinterpret_cast<const float4*>(
                &lds[(egBase + e) * ldsStride + k4 * 4]);
            a0[e] = fmaf(x.x, w00, a0[e]);
            a0[e] = fmaf(x.y, w01, a0[e]);
            a0[e] = fmaf(x.z, w02, a0[e]);
            a0[e] = fmaf(x.w, w03, a0[e]);
            a1[e] = fmaf(x.x, w10, a1[e]);
            a1[e] = fmaf(x.y, w11, a1[e]);
            a1[e] = fmaf(x.z, w12, a1[e]);
            a1[e] = fmaf(x.w, w13, a1[e]);
        }
    }
}

// ---------------- encoder: [N,16] -> MLP -> h fp32 + h_bf bf16 ------------
__global__ __launch_bounds__(NTHR) void encode_kernel(
    const float* __restrict__ nf, const float* __restrict__ W1,
    const float* __restrict__ b1, const float* __restrict__ W2,
    const float* __restrict__ b2, float* __restrict__ h,
    unsigned short* __restrict__ h_bf, int N) {
    __shared__ float xin[TILE * 16];
    __shared__ float hm[TILE * H];
    const int t = threadIdx.x;
    const int n0 = blockIdx.x * TILE;
    const int c0 = t & 63;
    const int eg = t >> 6;

    for (int i = t; i < TILE * 16; i += NTHR) {
        const int gi = n0 * 16 + i;
        xin[i] = (gi < N * 16) ? nf[gi] : 0.f;
    }
    __syncthreads();

    float a0[8], a1[8];
#pragma unroll
    for (int e = 0; e < 8; ++e) { a0[e] = 0.f; a1[e] = 0.f; }
    mlp_layer<4>(W1, xin, 16, c0, eg * 8, a0, a1);
    {
        const float bb0 = b1[c0], bb1 = b1[c0 + 64];
#pragma unroll
        for (int e = 0; e < 8; ++e) {
            hm[(eg * 8 + e) * H + c0] = gelu_fast(a0[e] + bb0);
            hm[(eg * 8 + e) * H + c0 + 64] = gelu_fast(a1[e] + bb1);
        }
    }
    __syncthreads();
#pragma unroll
    for (int e = 0; e < 8; ++e) { a0[e] = 0.f; a1[e] = 0.f; }
    mlp_layer<32>(W2, hm, H, c0, eg * 8, a0, a1);
    const float bb0 = b2[c0], bb1 = b2[c0 + 64];
#pragma unroll
    for (int e = 0; e < 8; ++e) {
        const int n = n0 + eg * 8 + e;
        if (n < N) {
            const float v0 = a0[e] + bb0, v1 = a1[e] + bb1;
            h[(size_t)n * H + c0] = v0;
            h[(size_t)n * H + c0 + 64] = v1;
            h_bf[(size_t)n * H + c0] = f2bf(v0);
            h_bf[(size_t)n * H + c0 + 64] = f2bf(v1);
        }
    }
}

// --------------- decoder: h -> GELU MLP -> out [N,8] ----------------------
__global__ __launch_bounds__(NTHR) void decode_kernel(
    const float* __restrict__ h, const float* __restrict__ W1,
    const float* __restrict__ b1, const float* __restrict__ W2,
    const float* __restrict__ b2, float* __restrict__ out, int N) {
    __shared__ float xin[TILE * H];
    __shared__ float hm[TILE * 132];
    const int t = threadIdx.x;
    const int n0 = blockIdx.x * TILE;
    const int c0 = t & 63;
    const int eg = t >> 6;
    {
        const int col = t & 127;
        for (int e = t >> 7; e < TILE; e += 2) {
            const int n = n0 + e;
            xin[e * H + col] = (n < N) ? h[(size_t)n * H + col] : 0.f;
        }
    }
    __syncthreads();

    float a0[8], a1[8];
#pragma unroll
    for (int e = 0; e < 8; ++e) { a0[e] = 0.f; a1[e] = 0.f; }
    mlp_layer<32>(W1, xin, H, c0, eg * 8, a0, a1);
    {
        const float bb0 = b1[c0], bb1 = b1[c0 + 64];
#pragma unroll
        for (int e = 0; e < 8; ++e) {
            hm[(eg * 8 + e) * 132 + c0] = gelu_fast(a0[e] + bb0);
            hm[(eg * 8 + e) * 132 + c0 + 64] = gelu_fast(a1[e] + bb1);
        }
    }
    __syncthreads();
    {
        const int e = t >> 3;
        const int o = t & 7;
        const int n = n0 + e;
        float acc = b2[o];
#pragma unroll 4
        for (int k = 0; k < H; ++k)
            acc = fmaf(hm[e * 132 + k], W2[k * 8 + o], acc);
        if (n < N) out[n * 8 + o] = acc;
    }
}

extern "C" void kernel_launch(void* const* d_in, const int* in_sizes, int n_in,
                              void* d_out, int out_size, void* d_ws,
                              size_t ws_size, hipStream_t stream) {
    (void)n_in; (void)out_size; (void)ws_size;
    const float* nf      = (const float*)d_in[0];
    const int*   ei      = (const int*)d_in[1];
    const float* enc_W1  = (const float*)d_in[2];
    const float* enc_b1  = (const float*)d_in[3];
    const float* enc_W2  = (const float*)d_in[4];
    const float* enc_b2  = (const float*)d_in[5];
    const float* edge_W1 = (const float*)d_in[6];
    const float* edge_b1 = (const float*)d_in[7];
    const float* edge_W2 = (const float*)d_in[8];
    const float* edge_b2 = (const float*)d_in[9];
    const float* node_W1 = (const float*)d_in[10];
    const float* node_b1 = (const float*)d_in[11];
    const float* node_W2 = (const float*)d_in[12];
    const float* node_b2 = (const float*)d_in[13];
    const float* dec_W1  = (const float*)d_in[14];
    const float* dec_b1  = (const float*)d_in[15];
    const float* dec_W2  = (const float*)d_in[16];
    const float* dec_b2  = (const float*)d_in[17];

    const int N = in_sizes[0] / 16;
    const int E = in_sizes[1] / 2;
    const int L = in_sizes[7] / H;  // edge_b1 is [L,H]
    const int numChunks = E / CHUNK + 1;

    // ---------------- workspace layout ----------------
    char* ws = (char*)d_ws;
    float* h    = (float*)ws;                    ws += (size_t)N * H * 4;
    float* Bf32 = (float*)ws;                    ws += (size_t)N * H * 4;
    unsigned short* h_bf = (unsigned short*)ws;  ws += (size_t)N * H * 2;
    unsigned short* A_bf = (unsigned short*)ws;  ws += (size_t)N * H * 2;
    unsigned short* aggB = (unsigned short*)ws;  ws += (size_t)N * H * 2;
    int* srcS     = (int*)ws;                    ws += (size_t)E * 4;
    int* deg      = (int*)ws;                    ws += (size_t)N * 4;
    int* rowStart = (int*)ws;                    ws += (size_t)(N + 1) * 4;
    int* cursor   = (int*)ws;                    ws += (size_t)N * 4;
    int* bsum     = (int*)ws;                    ws += (size_t)256 * 4;
    int* chunkLo  = (int*)ws;                    ws += (size_t)numChunks * 4;
    unsigned short* eW1t = (unsigned short*)ws;  ws += (size_t)L * 2 * H * H * 2;
    unsigned short* nW1tc = (unsigned short*)ws; ws += (size_t)L * 2 * H * H * 2;
    unsigned short* nW2t = (unsigned short*)ws;  ws += (size_t)L * H * H * 2;
    float* cvec   = (float*)ws;                  ws += (size_t)L * H * 4;

    const int* srcArr = ei;
    const int* dstArr = ei + E;

    // ---- weight prep (tiny) ----
    {
        const int t1 = L * 2 * H * H, t2 = L * H * H;
        prep_kernel<<<(t1 + 2 * t2 + NTHR - 1) / NTHR, NTHR, 0, stream>>>(
            edge_W1, node_W2, node_W1, eW1t, nW2t, nW1tc, t1, t2);
        wcomb_kernel<<<dim3(H + 1, L), H, 0, stream>>>(edge_W2, edge_b2,
                                                       node_W1, nW1tc, cvec);
    }

    // ---- sort edges by dst (hist + multiblock scan + merged finalize) ----
    hipMemsetAsync(deg, 0, (size_t)N * 4, stream);
    deg_kernel<<<(E + NTHR - 1) / NTHR, NTHR, 0, stream>>>(dstArr, deg, E);
    const int nScanB = (N + 1023) / 1024;
    scan1_kernel<<<nScanB, 1024, 0, stream>>>(deg, rowStart, bsum, N);
    scan2_kernel<<<1, 64, 0, stream>>>(bsum, nScanB);
    const int scan3Span = (N + 1 > numChunks) ? (N + 1) : numChunks;
    scan3_kernel<<<(scan3Span + NTHR - 1) / NTHR, NTHR, 0, stream>>>(
        rowStart, cursor, bsum, chunkLo, N, E, numChunks);
    const int finSpan = (N > E) ? N : E;
    finalize_kernel<<<(finSpan + NTHR - 1) / NTHR, NTHR, 0, stream>>>(
        rowStart, chunkLo, srcArr, dstArr, cursor, srcS, N, E);

    const int encBlocks  = (N + TILE - 1) / TILE;
    const int tileBlocks = (N + TE - 1) / TE;
    const int gatherBlks = (numChunks * 2 + 3) / 4;

    encode_kernel<<<encBlocks, NTHR, 0, stream>>>(nf, enc_W1, enc_b1, enc_W2,
                                                  enc_b2, h, h_bf, N);
    ab_kernel<<<tileBlocks, NTHR, 0, stream>>>(h_bf, eW1t, edge_b1, A_bf, Bf32,
                                               N);
    for (int l = 0; l < L; ++l) {
        edge_gather_kernel<<<gatherBlks, NTHR, 0, stream>>>(
            A_bf, Bf32, srcS, rowStart, chunkLo, aggB, N, E);
        if (l + 1 < L) {
            node_fused_kernel<true><<<tileBlocks, NTHR, 0, stream>>>(
                h, h_bf, aggB, deg, nW1tc + (size_t)l * 2 * H * H,
                node_b1 + (size_t)l * H, cvec + (size_t)l * H,
                nW2t + (size_t)l * H * H, node_b2 + (size_t)l * H,
                eW1t + (size_t)(l + 1) * 2 * H * H,
                edge_b1 + (size_t)(l + 1) * H, A_bf, Bf32, N);
        } else {
            node_fused_kernel<false><<<tileBlocks, NTHR, 0, stream>>>(
                h, h_bf, aggB, deg, nW1tc + (size_t)l * 2 * H * H,
                node_b1 + (size_t)l * H, cvec + (size_t)l * H,
                nW2t + (size_t)l * H * H, node_b2 + (size_t)l * H, nullptr,
                nullptr, nullptr, nullptr, N);
        }
    }
    decode_kernel<<<encBlocks, NTHR, 0, stream>>>(h, dec_W1, dec_b1, dec_W2,
                                                  dec_b2, (float*)d_out, N);
}

// Round 11
// 685.335 us; speedup vs baseline: 2.6475x; 1.0623x over previous
//
#include <hip/hip_runtime.h>
#include <math.h>

// FieldlineGraphForecaster round 10: r7 gather shape restored (one wave per
// chunk, 2 cols/lane — r9's column-split doubled per-chunk overhead and
// regressed), now with 8-edge ILP window (8 srcS + 8 A-row loads in flight).
// Kept from r9: merged finalize (chunkLo+scatter), chunkLo init in scan3.
// Numerics identical to r7 (5-term erf, same summation order): absmax 64.

constexpr int H = 128;
constexpr int NTHR = 256;
constexpr int TE = 64;    // rows per MFMA tile
constexpr int TILE = 32;  // rows per fp32 (enc/dec) tile
constexpr int CHUNK = 16; // sorted edges per chunk

using bf16x8 = __attribute__((ext_vector_type(8))) short;
using f32x4  = __attribute__((ext_vector_type(4))) float;

// Branchless GELU: A&S 7.1.26 erf (5-term), |eps|<=1.5e-7. DO NOT downgrade:
// 3-term (2.5e-5) fails the harness threshold (r6: absmax 80 > 78).
__device__ __forceinline__ float gelu_fast(float x) {
    const float u = fabsf(x) * 0.70710678118654752440f;
    const float t = __builtin_amdgcn_rcpf(fmaf(0.3275911f, u, 1.f));
    float p = fmaf(1.061405429f, t, -1.453152027f);
    p = fmaf(p, t, 1.421413741f);
    p = fmaf(p, t, -0.284496736f);
    p = fmaf(p, t, 0.254829592f);
    p = p * t;
    const float e = __expf(-u * u);
    float er = fmaf(-p, e, 1.f);  // erf(|x|/sqrt2)
    er = copysignf(er, x);
    return 0.5f * x * (1.f + er);
}

__device__ __forceinline__ unsigned short f2bf(float f) {
    unsigned int u = __builtin_bit_cast(unsigned int, f);
    u = (u + 0x7fffu + ((u >> 16) & 1u)) >> 16;
    return (unsigned short)u;
}

__device__ __forceinline__ float bf2f_lo(unsigned int v) {
    return __builtin_bit_cast(float, v << 16);
}
__device__ __forceinline__ float bf2f_hi(unsigned int v) {
    return __builtin_bit_cast(float, v & 0xffff0000u);
}

// ---- merged weight prep: eW1t, nW2t, nW1tc(top) in one kernel ------------
__global__ __launch_bounds__(NTHR) void prep_kernel(
    const float* __restrict__ eW1, const float* __restrict__ nW2,
    const float* __restrict__ nW1, unsigned short* __restrict__ eW1t,
    unsigned short* __restrict__ nW2t, unsigned short* __restrict__ nW1tc,
    int t1, int t2) {
    const int i = blockIdx.x * NTHR + threadIdx.x;
    if (i < t1) {
        const int per = 2 * H * H;
        const int l = i / per;
        const int r = i - l * per;
        const int n = r % H;
        const int k = r / H;
        eW1t[(size_t)l * per + n * 2 * H + k] = f2bf(eW1[i]);
    } else if (i < t1 + t2) {
        const int j = i - t1;
        const int per = H * H;
        const int l = j / per;
        const int r = j - l * per;
        const int n = r % H;
        const int k = r / H;
        nW2t[(size_t)l * per + n * H + k] = f2bf(nW2[j]);
    } else if (i < t1 + 2 * t2) {
        const int j = i - t1 - t2;
        const int per = H * H;
        const int l = j / per;
        const int r = j - l * per;
        const int k = r / H;
        const int o = r % H;
        nW1tc[(size_t)l * H * 2 * H + o * 2 * H + k] =
            f2bf(nW1[(size_t)l * 2 * H * H + k * H + o]);
    }
}

// ---- Wcomb[j][o] = sum_c eW2[j][c]*nW1[128+c][o] -> nW1tc bottom half; and
//      cvec[o] = sum_c eb2[c]*nW1[128+c][o] (j==128 block).
__global__ __launch_bounds__(H) void wcomb_kernel(
    const float* __restrict__ eW2, const float* __restrict__ eb2,
    const float* __restrict__ nW1, unsigned short* __restrict__ W1tc,
    float* __restrict__ cvec) {
    const int l = blockIdx.y;
    const int j = blockIdx.x;   // 0..128
    const int o = threadIdx.x;  // 0..127
    const float* w1 = nW1 + (size_t)l * 2 * H * H + (size_t)H * H;
    const float* row = (j < H) ? (eW2 + (size_t)l * H * H + (size_t)j * H)
                               : (eb2 + (size_t)l * H);
    float s = 0.f;
#pragma unroll 4
    for (int c = 0; c < H; ++c) s = fmaf(row[c], w1[(size_t)c * H + o], s);
    if (j < H)
        W1tc[(size_t)l * H * 2 * H + o * 2 * H + H + j] = f2bf(s);
    else
        cvec[(size_t)l * H + o] = s;
}

// ----------------------- sort-by-dst machinery ----------------------------
__global__ __launch_bounds__(NTHR) void deg_kernel(const int* __restrict__ dst,
                                                   int* __restrict__ deg, int E) {
    const int e = blockIdx.x * NTHR + threadIdx.x;
    if (e < E) atomicAdd(&deg[dst[e]], 1);
}

__global__ __launch_bounds__(1024) void scan1_kernel(
    const int* __restrict__ deg, int* __restrict__ out,
    int* __restrict__ bsum, int N) {
    __shared__ int buf[1024];
    const int t = threadIdx.x;
    const int i = blockIdx.x * 1024 + t;
    const int x = (i < N) ? deg[i] : 0;
    buf[t] = x;
    __syncthreads();
    int v = x;
    for (int off = 1; off < 1024; off <<= 1) {
        const int y = (t >= off) ? buf[t - off] : 0;
        __syncthreads();
        v += y;
        buf[t] = v;
        __syncthreads();
    }
    if (i < N) out[i] = v - x;  // block-local exclusive
    if (t == 1023) bsum[blockIdx.x] = v;
}

__global__ void scan2_kernel(int* __restrict__ bsum, int nb) {
    if (threadIdx.x == 0) {
        int acc = 0;
        for (int i = 0; i < nb; ++i) {
            const int t = bsum[i];
            bsum[i] = acc;
            acc += t;
        }
    }
}

// also initializes chunkLo sentinel (saves a memset dispatch)
__global__ __launch_bounds__(NTHR) void scan3_kernel(
    int* __restrict__ out, int* __restrict__ cursor,
    const int* __restrict__ bsum, int* __restrict__ chunkLo, int N, int E,
    int numChunks) {
    const int i = blockIdx.x * NTHR + threadIdx.x;
    if (i < N) {
        const int v = out[i] + bsum[i >> 10];
        out[i] = v;
        cursor[i] = v;
    } else if (i == N) {
        out[N] = E;
    }
    if (i < numChunks) chunkLo[i] = 0x7fffffff;
}

// merged: chunkLo atomicMin + dst-sorted scatter (both depend only on scan3)
// srcS holds BYTE offsets into A (src * H * 2)
__global__ __launch_bounds__(NTHR) void finalize_kernel(
    const int* __restrict__ rowStart, int* __restrict__ chunkLo,
    const int* __restrict__ src, const int* __restrict__ dst,
    int* __restrict__ cursor, int* __restrict__ srcS, int N, int E) {
    const int i = blockIdx.x * NTHR + threadIdx.x;
    if (i < N) atomicMin(&chunkLo[rowStart[i] / CHUNK], i);
    if (i < E) {
        const int pos = atomicAdd(&cursor[dst[i]], 1);
        srcS[pos] = src[i] << 8;  // * 256 bytes per A row
    }
}

// ---- A/B kernel (layer 0 only): A = h@W1_top (bf16), B = h@W1_bot+b1 -----
__global__ __launch_bounds__(NTHR) void ab_kernel(
    const unsigned short* __restrict__ h_bf,
    const unsigned short* __restrict__ W1t,  // [128 cols][256 k]
    const float* __restrict__ b1, unsigned short* __restrict__ A,
    float* __restrict__ Bout, int N) {
    __shared__ __align__(16) unsigned short X[TE * H];  // 16KB
    const int t = threadIdx.x;
    const int lane = t & 63;
    const int w = t >> 6;
    const int n0 = blockIdx.x * TE;
    const int l15 = lane & 15;
    const int lq = lane >> 4;

#pragma unroll
    for (int i = 0; i < 4; ++i) {
        const int c = i * NTHR + t;
        const int row = c >> 4;
        const int col8 = c & 15;
        const int n = n0 + row;
        const int4 v = (n < N)
            ? *reinterpret_cast<const int4*>(h_bf + (size_t)n * H + col8 * 8)
            : make_int4(0, 0, 0, 0);
        const int byteoff = row * 256 + ((col8 * 16) ^ ((row & 7) << 4));
        *reinterpret_cast<int4*>(reinterpret_cast<char*>(X) + byteoff) = v;
    }

    const int half = w >> 1;  // 0 -> A, 1 -> B
    const int cbase = (w & 1) * 64;
    bf16x8 Bf[4][4];
#pragma unroll
    for (int cg = 0; cg < 4; ++cg) {
        const int col = cbase + cg * 16 + l15;
#pragma unroll
        for (int s = 0; s < 4; ++s)
            Bf[cg][s] = *reinterpret_cast<const bf16x8*>(
                W1t + (size_t)col * 256 + half * 128 + s * 32 + lq * 8);
    }
    __syncthreads();

    f32x4 acc[4][4];
#pragma unroll
    for (int rg = 0; rg < 4; ++rg)
#pragma unroll
        for (int cg = 0; cg < 4; ++cg) acc[rg][cg] = (f32x4)0.f;

#pragma unroll
    for (int s = 0; s < 4; ++s) {
        bf16x8 a[4];
#pragma unroll
        for (int rg = 0; rg < 4; ++rg) {
            const int row = rg * 16 + l15;
            const int byteoff = row * 256 + ((s * 64 + lq * 16) ^ ((row & 7) << 4));
            a[rg] = *reinterpret_cast<const bf16x8*>(
                reinterpret_cast<const char*>(X) + byteoff);
        }
#pragma unroll
        for (int rg = 0; rg < 4; ++rg)
#pragma unroll
            for (int cg = 0; cg < 4; ++cg)
                acc[rg][cg] = __builtin_amdgcn_mfma_f32_16x16x32_bf16(
                    a[rg], Bf[cg][s], acc[rg][cg], 0, 0, 0);
    }

#pragma unroll
    for (int cg = 0; cg < 4; ++cg) {
        const int col = cbase + cg * 16 + l15;
        const float bb = (half == 1) ? b1[col] : 0.f;
#pragma unroll
        for (int rg = 0; rg < 4; ++rg) {
#pragma unroll
            for (int r = 0; r < 4; ++r) {
                const int row = rg * 16 + lq * 4 + r;
                const int n = n0 + row;
                if (n < N) {
                    if (half == 0)
                        A[(size_t)n * H + col] = f2bf(acc[rg][cg][r]);
                    else
                        Bout[(size_t)n * H + col] = acc[rg][cg][r] + bb;
                }
            }
        }
    }
}

// ---- edge gather: one wave per chunk, 2 cols/lane, 8-edge ILP window -----
__global__ __launch_bounds__(NTHR) void edge_gather_kernel(
    const unsigned short* __restrict__ A, const float* __restrict__ B,
    const int* __restrict__ srcS, const int* __restrict__ rowStart,  // N+1
    const int* __restrict__ chunkLo, unsigned short* __restrict__ aggB,
    int N, int E) {
    const int lane = threadIdx.x & 63;
    const int c = blockIdx.x * 4 + (threadIdx.x >> 6);
    const int nWaves = E / CHUNK + 1;
    if (c >= nWaves) return;
    int n = chunkLo[c];
    if (n >= N) return;  // sentinel: no node starts in this chunk
    const int Wend = (c + 1) * CHUNK;
    const int c2 = lane * 2;
    const char* Abase = (const char*)A + (size_t)(lane * 4);
    int r0 = rowStart[n];
    while (true) {
        const int r1 = rowStart[n + 1];
        const float2 bv = *reinterpret_cast<const float2*>(B + (size_t)n * H + c2);
        float s0 = 0.f, s1 = 0.f;
        int e = r0;
        // 8-edge ILP window: 8 srcS scalar loads + 8 A-row vector loads in
        // flight before the gelu chain. Summation order = edge order
        // (identical to 4x version) -> bit-identical results.
        for (; e + 8 <= r1; e += 8) {
            const int sa = srcS[e];
            const int sb = srcS[e + 1];
            const int sc = srcS[e + 2];
            const int sd = srcS[e + 3];
            const int se = srcS[e + 4];
            const int sf = srcS[e + 5];
            const int sg = srcS[e + 6];
            const int sh = srcS[e + 7];
            const unsigned int va = *reinterpret_cast<const unsigned int*>(Abase + sa);
            const unsigned int vb = *reinterpret_cast<const unsigned int*>(Abase + sb);
            const unsigned int vc = *reinterpret_cast<const unsigned int*>(Abase + sc);
            const unsigned int vd = *reinterpret_cast<const unsigned int*>(Abase + sd);
            const unsigned int ve = *reinterpret_cast<const unsigned int*>(Abase + se);
            const unsigned int vf = *reinterpret_cast<const unsigned int*>(Abase + sf);
            const unsigned int vg = *reinterpret_cast<const unsigned int*>(Abase + sg);
            const unsigned int vh = *reinterpret_cast<const unsigned int*>(Abase + sh);
            s0 += gelu_fast(bf2f_lo(va) + bv.x);
            s1 += gelu_fast(bf2f_hi(va) + bv.y);
            s0 += gelu_fast(bf2f_lo(vb) + bv.x);
            s1 += gelu_fast(bf2f_hi(vb) + bv.y);
            s0 += gelu_fast(bf2f_lo(vc) + bv.x);
            s1 += gelu_fast(bf2f_hi(vc) + bv.y);
            s0 += gelu_fast(bf2f_lo(vd) + bv.x);
            s1 += gelu_fast(bf2f_hi(vd) + bv.y);
            s0 += gelu_fast(bf2f_lo(ve) + bv.x);
            s1 += gelu_fast(bf2f_hi(ve) + bv.y);
            s0 += gelu_fast(bf2f_lo(vf) + bv.x);
            s1 += gelu_fast(bf2f_hi(vf) + bv.y);
            s0 += gelu_fast(bf2f_lo(vg) + bv.x);
            s1 += gelu_fast(bf2f_hi(vg) + bv.y);
            s0 += gelu_fast(bf2f_lo(vh) + bv.x);
            s1 += gelu_fast(bf2f_hi(vh) + bv.y);
        }
        for (; e + 4 <= r1; e += 4) {
            const int sa = srcS[e];
            const int sb = srcS[e + 1];
            const int sc = srcS[e + 2];
            const int sd = srcS[e + 3];
            const unsigned int va = *reinterpret_cast<const unsigned int*>(Abase + sa);
            const unsigned int vb = *reinterpret_cast<const unsigned int*>(Abase + sb);
            const unsigned int vc = *reinterpret_cast<const unsigned int*>(Abase + sc);
            const unsigned int vd = *reinterpret_cast<const unsigned int*>(Abase + sd);
            s0 += gelu_fast(bf2f_lo(va) + bv.x);
            s1 += gelu_fast(bf2f_hi(va) + bv.y);
            s0 += gelu_fast(bf2f_lo(vb) + bv.x);
            s1 += gelu_fast(bf2f_hi(vb) + bv.y);
            s0 += gelu_fast(bf2f_lo(vc) + bv.x);
            s1 += gelu_fast(bf2f_hi(vc) + bv.y);
            s0 += gelu_fast(bf2f_lo(vd) + bv.x);
            s1 += gelu_fast(bf2f_hi(vd) + bv.y);
        }
        for (; e < r1; ++e) {
            const unsigned int av =
                *reinterpret_cast<const unsigned int*>(Abase + srcS[e]);
            s0 += gelu_fast(bf2f_lo(av) + bv.x);
            s1 += gelu_fast(bf2f_hi(av) + bv.y);
        }
        const unsigned int packed =
            (unsigned int)f2bf(s0) | ((unsigned int)f2bf(s1) << 16);
        *reinterpret_cast<unsigned int*>(aggB + (size_t)n * H + c2) = packed;
        if (++n >= N) break;
        r0 = r1;
        if (r0 >= Wend) break;
    }
}

// ---- fused node update (+ next-layer A/B production) ---------------------
// h += MLP([h | aggB]; W1'=[nW1_top;Wcomb], b1'=b1+deg*cvec); refresh h_bf.
// If PROD: A_out = h_new@eW1_top(next), B_out = h_new@eW1_bot(next)+eb1(next).
template <bool PROD>
__global__ __launch_bounds__(NTHR) void node_fused_kernel(
    float* __restrict__ h, unsigned short* __restrict__ h_bf,
    const unsigned short* __restrict__ aggB, const int* __restrict__ deg,
    const unsigned short* __restrict__ W1tc, const float* __restrict__ b1,
    const float* __restrict__ cvec, const unsigned short* __restrict__ W2t,
    const float* __restrict__ b2, const unsigned short* __restrict__ eW1tN,
    const float* __restrict__ eb1N, unsigned short* __restrict__ A_out,
    float* __restrict__ B_out, int N) {
    __shared__ __align__(16) unsigned short X[TE * 256];  // 32KB
    __shared__ int degS[TE];
    const int t = threadIdx.x;
    const int lane = t & 63;
    const int w = t >> 6;
    const int n0 = blockIdx.x * TE;
    const int l15 = lane & 15;
    const int lq = lane >> 4;

    if (t < TE) degS[t] = (n0 + t < N) ? deg[n0 + t] : 0;
#pragma unroll
    for (int i = 0; i < 8; ++i) {
        const int c = i * NTHR + t;
        const int row = c >> 5;
        const int col8 = c & 31;
        const int n = n0 + row;
        int4 v = make_int4(0, 0, 0, 0);
        if (n < N) {
            const unsigned short* srcp = (col8 < 16) ? h_bf : aggB;
            v = *reinterpret_cast<const int4*>(srcp + (size_t)n * H +
                                               (col8 & 15) * 8);
        }
        const int byteoff = row * 512 + ((col8 * 16) ^ ((row & 7) << 4));
        *reinterpret_cast<int4*>(reinterpret_cast<char*>(X) + byteoff) = v;
    }

    bf16x8 B1[2][8];
#pragma unroll
    for (int cg = 0; cg < 2; ++cg) {
        const int col = w * 32 + cg * 16 + l15;
#pragma unroll
        for (int s = 0; s < 8; ++s)
            B1[cg][s] = *reinterpret_cast<const bf16x8*>(
                W1tc + (size_t)col * 256 + s * 32 + lq * 8);
    }
    __syncthreads();

    f32x4 acc[4][2];
#pragma unroll
    for (int rg = 0; rg < 4; ++rg)
#pragma unroll
        for (int cg = 0; cg < 2; ++cg) acc[rg][cg] = (f32x4)0.f;

#pragma unroll
    for (int s = 0; s < 8; ++s) {
        bf16x8 a[4];
#pragma unroll
        for (int rg = 0; rg < 4; ++rg) {
            const int row = rg * 16 + l15;
            const int byteoff = row * 512 + ((s * 64 + lq * 16) ^ ((row & 7) << 4));
            a[rg] = *reinterpret_cast<const bf16x8*>(
                reinterpret_cast<const char*>(X) + byteoff);
        }
#pragma unroll
        for (int rg = 0; rg < 4; ++rg)
#pragma unroll
            for (int cg = 0; cg < 2; ++cg)
                acc[rg][cg] = __builtin_amdgcn_mfma_f32_16x16x32_bf16(
                    a[rg], B1[cg][s], acc[rg][cg], 0, 0, 0);
    }
    __syncthreads();

    // L1 epilogue: gelu(acc + b1 + deg*cvec) -> hm (LDS bytes 0..16K)
#pragma unroll
    for (int cg = 0; cg < 2; ++cg) {
        const int col = w * 32 + cg * 16 + l15;
        const float bb = b1[col];
        const float cc = cvec[col];
#pragma unroll
        for (int rg = 0; rg < 4; ++rg) {
#pragma unroll
            for (int r = 0; r < 4; ++r) {
                const int row = rg * 16 + lq * 4 + r;
                const float v =
                    gelu_fast(acc[rg][cg][r] + bb + (float)degS[row] * cc);
                const int byteoff = row * 256 + ((col * 2) ^ ((row & 7) << 4));
                *reinterpret_cast<unsigned short*>(
                    reinterpret_cast<char*>(X) + byteoff) = f2bf(v);
            }
        }
    }

    bf16x8 B2[2][4];
#pragma unroll
    for (int cg = 0; cg < 2; ++cg) {
        const int col = w * 32 + cg * 16 + l15;
#pragma unroll
        for (int s = 0; s < 4; ++s)
            B2[cg][s] = *reinterpret_cast<const bf16x8*>(
                W2t + (size_t)col * 128 + s * 32 + lq * 8);
    }
    __syncthreads();

    f32x4 acc2[4][2];
#pragma unroll
    for (int rg = 0; rg < 4; ++rg)
#pragma unroll
        for (int cg = 0; cg < 2; ++cg) acc2[rg][cg] = (f32x4)0.f;

#pragma unroll
    for (int s = 0; s < 4; ++s) {
        bf16x8 a[4];
#pragma unroll
        for (int rg = 0; rg < 4; ++rg) {
            const int row = rg * 16 + l15;
            const int byteoff = row * 256 + ((s * 64 + lq * 16) ^ ((row & 7) << 4));
            a[rg] = *reinterpret_cast<const bf16x8*>(
                reinterpret_cast<const char*>(X) + byteoff);
        }
#pragma unroll
        for (int rg = 0; rg < 4; ++rg)
#pragma unroll
            for (int cg = 0; cg < 2; ++cg)
                acc2[rg][cg] = __builtin_amdgcn_mfma_f32_16x16x32_bf16(
                    a[rg], B2[cg][s], acc2[rg][cg], 0, 0, 0);
    }

    // residual write: h += update; refresh h_bf; h_new bf16 -> LDS @16KB
#pragma unroll
    for (int cg = 0; cg < 2; ++cg) {
        const int col = w * 32 + cg * 16 + l15;
        const float bb = b2[col];
#pragma unroll
        for (int rg = 0; rg < 4; ++rg) {
#pragma unroll
            for (int r = 0; r < 4; ++r) {
                const int row = rg * 16 + lq * 4 + r;
                const int n = n0 + row;
                if (n < N) {
                    const float hv = h[(size_t)n * H + col] + acc2[rg][cg][r] + bb;
                    h[(size_t)n * H + col] = hv;
                    const unsigned short hb = f2bf(hv);
                    h_bf[(size_t)n * H + col] = hb;
                    if (PROD) {
                        const int byteoff =
                            16384 + row * 256 + ((col * 2) ^ ((row & 7) << 4));
                        *reinterpret_cast<unsigned short*>(
                            reinterpret_cast<char*>(X) + byteoff) = hb;
                    }
                } else if (PROD) {
                    const int byteoff =
                        16384 + row * 256 + ((col * 2) ^ ((row & 7) << 4));
                    *reinterpret_cast<unsigned short*>(
                        reinterpret_cast<char*>(X) + byteoff) = 0;
                }
            }
        }
    }

    if (PROD) {
        bf16x8 B3[2][4], B4[2][4];
#pragma unroll
        for (int cg = 0; cg < 2; ++cg) {
            const int col = w * 32 + cg * 16 + l15;
#pragma unroll
            for (int s = 0; s < 4; ++s) {
                B3[cg][s] = *reinterpret_cast<const bf16x8*>(
                    eW1tN + (size_t)col * 256 + s * 32 + lq * 8);
                B4[cg][s] = *reinterpret_cast<const bf16x8*>(
                    eW1tN + (size_t)col * 256 + 128 + s * 32 + lq * 8);
            }
        }
        __syncthreads();

        f32x4 acc3[4][2], acc4[4][2];
#pragma unroll
        for (int rg = 0; rg < 4; ++rg)
#pragma unroll
            for (int cg = 0; cg < 2; ++cg) {
                acc3[rg][cg] = (f32x4)0.f;
                acc4[rg][cg] = (f32x4)0.f;
            }

#pragma unroll
        for (int s = 0; s < 4; ++s) {
            bf16x8 a[4];
#pragma unroll
            for (int rg = 0; rg < 4; ++rg) {
                const int row = rg * 16 + l15;
                const int byteoff =
                    16384 + row * 256 + ((s * 64 + lq * 16) ^ ((row & 7) << 4));
                a[rg] = *reinterpret_cast<const bf16x8*>(
                    reinterpret_cast<const char*>(X) + byteoff);
            }
#pragma unroll
            for (int rg = 0; rg < 4; ++rg)
#pragma unroll
                for (int cg = 0; cg < 2; ++cg) {
                    acc3[rg][cg] = __builtin_amdgcn_mfma_f32_16x16x32_bf16(
                        a[rg], B3[cg][s], acc3[rg][cg], 0, 0, 0);
                    acc4[rg][cg] = __builtin_amdgcn_mfma_f32_16x16x32_bf16(
                        a[rg], B4[cg][s], acc4[rg][cg], 0, 0, 0);
                }
        }

#pragma unroll
        for (int cg = 0; cg < 2; ++cg) {
            const int col = w * 32 + cg * 16 + l15;
            const float bb = eb1N[col];
#pragma unroll
            for (int rg = 0; rg < 4; ++rg) {
#pragma unroll
                for (int r = 0; r < 4; ++r) {
                    const int row = rg * 16 + lq * 4 + r;
                    const int n = n0 + row;
                    if (n < N) {
                        A_out[(size_t)n * H + col] = f2bf(acc3[rg][cg][r]);
                        B_out[(size_t)n * H + col] = acc4[rg][cg][r] + bb;
                    }
                }
            }
        }
    }
}

// ---------------- fp32 helper for encoder/decoder -------------------------
template <int K4>
__device__ __forceinline__ void mlp_layer(const float* __restrict__ W,
                                          const float* lds, int ldsStride,
                                          int c0, int egBase,
                                          float a0[8], float a1[8]) {
#pragma unroll 2
    for (int k4 = 0; k4 < K4; ++k4) {
        const float w00 = W[(k4 * 4 + 0) * H + c0];
        const float w01 = W[(k4 * 4 + 1) * H + c0];
        const float w02 = W[(k4 * 4 + 2) * H + c0];
        const float w03 = W[(k4 * 4 + 3) * H + c0];
        const float w10 = W[(k4 * 4 + 0) * H + c0 + 64];
        const float w11 = W[(k4 * 4 + 1) * H + c0 + 64];
        const float w12 = W[(k4 * 4 + 2) * H + c0 + 64];
        const float w13 = W[(k4 * 4 + 3) * H + c0 + 64];
#pragma unroll
        for (int e = 0; e < 8; ++e) {
            const float4 x = *reinterpret_cast<const float4*>(
                &lds[(egBase + e) * ldsStride + k4 * 4]);
            a0[e] = fmaf(x.x, w00, a0[e]);
            a0[e] = fmaf(x.y, w01, a0[e]);
            a0[e] = fmaf(x.z, w02, a0[e]);
            a0[e] = fmaf(x.w, w03, a0[e]);
            a1[e] = fmaf(x.x, w10, a1[e]);
            a1[e] = fmaf(x.y, w11, a1[e]);
            a1[e] = fmaf(x.z, w12, a1[e]);
            a1[e] = fmaf(x.w, w13, a1[e]);
        }
    }
}

// ---------------- encoder: [N,16] -> MLP -> h fp32 + h_bf bf16 ------------
__global__ __launch_bounds__(NTHR) void encode_kernel(
    const float* __restrict__ nf, const float* __restrict__ W1,
    const float* __restrict__ b1, const float* __restrict__ W2,
    const float* __restrict__ b2, float* __restrict__ h,
    unsigned short* __restrict__ h_bf, int N) {
    __shared__ float xin[TILE * 16];
    __shared__ float hm[TILE * H];
    const int t = threadIdx.x;
    const int n0 = blockIdx.x * TILE;
    const int c0 = t & 63;
    const int eg = t >> 6;

    for (int i = t; i < TILE * 16; i += NTHR) {
        const int gi = n0 * 16 + i;
        xin[i] = (gi < N * 16) ? nf[gi] : 0.f;
    }
    __syncthreads();

    float a0[8], a1[8];
#pragma unroll
    for (int e = 0; e < 8; ++e) { a0[e] = 0.f; a1[e] = 0.f; }
    mlp_layer<4>(W1, xin, 16, c0, eg * 8, a0, a1);
    {
        const float bb0 = b1[c0], bb1 = b1[c0 + 64];
#pragma unroll
        for (int e = 0; e < 8; ++e) {
            hm[(eg * 8 + e) * H + c0] = gelu_fast(a0[e] + bb0);
            hm[(eg * 8 + e) * H + c0 + 64] = gelu_fast(a1[e] + bb1);
        }
    }
    __syncthreads();
#pragma unroll
    for (int e = 0; e < 8; ++e) { a0[e] = 0.f; a1[e] = 0.f; }
    mlp_layer<32>(W2, hm, H, c0, eg * 8, a0, a1);
    const float bb0 = b2[c0], bb1 = b2[c0 + 64];
#pragma unroll
    for (int e = 0; e < 8; ++e) {
        const int n = n0 + eg * 8 + e;
        if (n < N) {
            const float v0 = a0[e] + bb0, v1 = a1[e] + bb1;
            h[(size_t)n * H + c0] = v0;
            h[(size_t)n * H + c0 + 64] = v1;
            h_bf[(size_t)n * H + c0] = f2bf(v0);
            h_bf[(size_t)n * H + c0 + 64] = f2bf(v1);
        }
    }
}

// --------------- decoder: h -> GELU MLP -> out [N,8] ----------------------
__global__ __launch_bounds__(NTHR) void decode_kernel(
    const float* __restrict__ h, const float* __restrict__ W1,
    const float* __restrict__ b1, const float* __restrict__ W2,
    const float* __restrict__ b2, float* __restrict__ out, int N) {
    __shared__ float xin[TILE * H];
    __shared__ float hm[TILE * 132];
    const int t = threadIdx.x;
    const int n0 = blockIdx.x * TILE;
    const int c0 = t & 63;
    const int eg = t >> 6;
    {
        const int col = t & 127;
        for (int e = t >> 7; e < TILE; e += 2) {
            const int n = n0 + e;
            xin[e * H + col] = (n < N) ? h[(size_t)n * H + col] : 0.f;
        }
    }
    __syncthreads();

    float a0[8], a1[8];
#pragma unroll
    for (int e = 0; e < 8; ++e) { a0[e] = 0.f; a1[e] = 0.f; }
    mlp_layer<32>(W1, xin, H, c0, eg * 8, a0, a1);
    {
        const float bb0 = b1[c0], bb1 = b1[c0 + 64];
#pragma unroll
        for (int e = 0; e < 8; ++e) {
            hm[(eg * 8 + e) * 132 + c0] = gelu_fast(a0[e] + bb0);
            hm[(eg * 8 + e) * 132 + c0 + 64] = gelu_fast(a1[e] + bb1);
        }
    }
    __syncthreads();
    {
        const int e = t >> 3;
        const int o = t & 7;
        const int n = n0 + e;
        float acc = b2[o];
#pragma unroll 4
        for (int k = 0; k < H; ++k)
            acc = fmaf(hm[e * 132 + k], W2[k * 8 + o], acc);
        if (n < N) out[n * 8 + o] = acc;
    }
}

extern "C" void kernel_launch(void* const* d_in, const int* in_sizes, int n_in,
                              void* d_out, int out_size, void* d_ws,
                              size_t ws_size, hipStream_t stream) {
    (void)n_in; (void)out_size; (void)ws_size;
    const float* nf      = (const float*)d_in[0];
    const int*   ei      = (const int*)d_in[1];
    const float* enc_W1  = (const float*)d_in[2];
    const float* enc_b1  = (const float*)d_in[3];
    const float* enc_W2  = (const float*)d_in[4];
    const float* enc_b2  = (const float*)d_in[5];
    const float* edge_W1 = (const float*)d_in[6];
    const float* edge_b1 = (const float*)d_in[7];
    const float* edge_W2 = (const float*)d_in[8];
    const float* edge_b2 = (const float*)d_in[9];
    const float* node_W1 = (const float*)d_in[10];
    const float* node_b1 = (const float*)d_in[11];
    const float* node_W2 = (const float*)d_in[12];
    const float* node_b2 = (const float*)d_in[13];
    const float* dec_W1  = (const float*)d_in[14];
    const float* dec_b1  = (const float*)d_in[15];
    const float* dec_W2  = (const float*)d_in[16];
    const float* dec_b2  = (const float*)d_in[17];

    const int N = in_sizes[0] / 16;
    const int E = in_sizes[1] / 2;
    const int L = in_sizes[7] / H;  // edge_b1 is [L,H]
    const int numChunks = E / CHUNK + 1;

    // ---------------- workspace layout ----------------
    char* ws = (char*)d_ws;
    float* h    = (float*)ws;                    ws += (size_t)N * H * 4;
    float* Bf32 = (float*)ws;                    ws += (size_t)N * H * 4;
    unsigned short* h_bf = (unsigned short*)ws;  ws += (size_t)N * H * 2;
    unsigned short* A_bf = (unsigned short*)ws;  ws += (size_t)N * H * 2;
    unsigned short* aggB = (unsigned short*)ws;  ws += (size_t)N * H * 2;
    int* srcS     = (int*)ws;                    ws += (size_t)E * 4;
    int* deg      = (int*)ws;                    ws += (size_t)N * 4;
    int* rowStart = (int*)ws;                    ws += (size_t)(N + 1) * 4;
    int* cursor   = (int*)ws;                    ws += (size_t)N * 4;
    int* bsum     = (int*)ws;                    ws += (size_t)256 * 4;
    int* chunkLo  = (int*)ws;                    ws += (size_t)numChunks * 4;
    unsigned short* eW1t = (unsigned short*)ws;  ws += (size_t)L * 2 * H * H * 2;
    unsigned short* nW1tc = (unsigned short*)ws; ws += (size_t)L * 2 * H * H * 2;
    unsigned short* nW2t = (unsigned short*)ws;  ws += (size_t)L * H * H * 2;
    float* cvec   = (float*)ws;                  ws += (size_t)L * H * 4;

    const int* srcArr = ei;
    const int* dstArr = ei + E;

    // ---- weight prep (tiny) ----
    {
        const int t1 = L * 2 * H * H, t2 = L * H * H;
        prep_kernel<<<(t1 + 2 * t2 + NTHR - 1) / NTHR, NTHR, 0, stream>>>(
            edge_W1, node_W2, node_W1, eW1t, nW2t, nW1tc, t1, t2);
        wcomb_kernel<<<dim3(H + 1, L), H, 0, stream>>>(edge_W2, edge_b2,
                                                       node_W1, nW1tc, cvec);
    }

    // ---- sort edges by dst (hist + multiblock scan + merged finalize) ----
    hipMemsetAsync(deg, 0, (size_t)N * 4, stream);
    deg_kernel<<<(E + NTHR - 1) / NTHR, NTHR, 0, stream>>>(dstArr, deg, E);
    const int nScanB = (N + 1023) / 1024;
    scan1_kernel<<<nScanB, 1024, 0, stream>>>(deg, rowStart, bsum, N);
    scan2_kernel<<<1, 64, 0, stream>>>(bsum, nScanB);
    const int scan3Span = (N + 1 > numChunks) ? (N + 1) : numChunks;
    scan3_kernel<<<(scan3Span + NTHR - 1) / NTHR, NTHR, 0, stream>>>(
        rowStart, cursor, bsum, chunkLo, N, E, numChunks);
    const int finSpan = (N > E) ? N : E;
    finalize_kernel<<<(finSpan + NTHR - 1) / NTHR, NTHR, 0, stream>>>(
        rowStart, chunkLo, srcArr, dstArr, cursor, srcS, N, E);

    const int encBlocks  = (N + TILE - 1) / TILE;
    const int tileBlocks = (N + TE - 1) / TE;
    const int gatherBlks = (numChunks + 3) / 4;

    encode_kernel<<<encBlocks, NTHR, 0, stream>>>(nf, enc_W1, enc_b1, enc_W2,
                                                  enc_b2, h, h_bf, N);
    ab_kernel<<<tileBlocks, NTHR, 0, stream>>>(h_bf, eW1t, edge_b1, A_bf, Bf32,
                                               N);
    for (int l = 0; l < L; ++l) {
        edge_gather_kernel<<<gatherBlks, NTHR, 0, stream>>>(
            A_bf, Bf32, srcS, rowStart, chunkLo, aggB, N, E);
        if (l + 1 < L) {
            node_fused_kernel<true><<<tileBlocks, NTHR, 0, stream>>>(
                h, h_bf, aggB, deg, nW1tc + (size_t)l * 2 * H * H,
                node_b1 + (size_t)l * H, cvec + (size_t)l * H,
                nW2t + (size_t)l * H * H, node_b2 + (size_t)l * H,
                eW1t + (size_t)(l + 1) * 2 * H * H,
                edge_b1 + (size_t)(l + 1) * H, A_bf, Bf32, N);
        } else {
            node_fused_kernel<false><<<tileBlocks, NTHR, 0, stream>>>(
                h, h_bf, aggB, deg, nW1tc + (size_t)l * 2 * H * H,
                node_b1 + (size_t)l * H, cvec + (size_t)l * H,
                nW2t + (size_t)l * H * H, node_b2 + (size_t)l * H, nullptr,
                nullptr, nullptr, nullptr, N);
        }
    }
    decode_kernel<<<encBlocks, NTHR, 0, stream>>>(h, dec_W1, dec_b1, dec_W2,
                                                  dec_b2, (float*)d_out, N);
}

// Round 12
// 676.386 us; speedup vs baseline: 2.6826x; 1.0132x over previous
//
#include <hip/hip_runtime.h>
#include <math.h>

// FieldlineGraphForecaster round 11: consolidation, bit-identical numerics.
//  - encode+ab fused (32-row tiles): h_bf passes through swizzled LDS.
//  - wcomb + deg-zero folded into prep_kernel (block-range segments).
//  - gather/node/decode/scan/finalize identical to r10 (best, 685us).

constexpr int H = 128;
constexpr int NTHR = 256;
constexpr int TE = 64;    // rows per MFMA tile (node kernel)
constexpr int TILE = 32;  // rows per enc/ab/dec tile
constexpr int CHUNK = 16; // sorted edges per chunk

using bf16x8 = __attribute__((ext_vector_type(8))) short;
using f32x4  = __attribute__((ext_vector_type(4))) float;

// Branchless GELU: A&S 7.1.26 erf (5-term), |eps|<=1.5e-7. DO NOT downgrade:
// 3-term (2.5e-5) fails the harness threshold (r6: absmax 80 > 78).
__device__ __forceinline__ float gelu_fast(float x) {
    const float u = fabsf(x) * 0.70710678118654752440f;
    const float t = __builtin_amdgcn_rcpf(fmaf(0.3275911f, u, 1.f));
    float p = fmaf(1.061405429f, t, -1.453152027f);
    p = fmaf(p, t, 1.421413741f);
    p = fmaf(p, t, -0.284496736f);
    p = fmaf(p, t, 0.254829592f);
    p = p * t;
    const float e = __expf(-u * u);
    float er = fmaf(-p, e, 1.f);  // erf(|x|/sqrt2)
    er = copysignf(er, x);
    return 0.5f * x * (1.f + er);
}

__device__ __forceinline__ unsigned short f2bf(float f) {
    unsigned int u = __builtin_bit_cast(unsigned int, f);
    u = (u + 0x7fffu + ((u >> 16) & 1u)) >> 16;
    return (unsigned short)u;
}

__device__ __forceinline__ float bf2f_lo(unsigned int v) {
    return __builtin_bit_cast(float, v << 16);
}
__device__ __forceinline__ float bf2f_hi(unsigned int v) {
    return __builtin_bit_cast(float, v & 0xffff0000u);
}

// ---- merged prep: eW1t, nW2t, nW1tc(top), wcomb(bottom+cvec), deg=0 ------
// seg A: [0, t1)              edge_W1 -> eW1t [l][128][256]
// seg B: [t1, t1+t2)          node_W2 -> nW2t [l][128][128]
// seg C: [t1+t2, t1+2t2)      node_W1 top -> nW1tc (k 0..127)
// seg D: [t1+2t2, +L*129*128) Wcomb/cvec -> nW1tc bottom + cvec
// plus: deg[i]=0 for i<N (runs before deg_kernel on the stream).
__global__ __launch_bounds__(NTHR) void prep_kernel(
    const float* __restrict__ eW1, const float* __restrict__ nW2,
    const float* __restrict__ nW1, const float* __restrict__ eW2,
    const float* __restrict__ eb2, unsigned short* __restrict__ eW1t,
    unsigned short* __restrict__ nW2t, unsigned short* __restrict__ nW1tc,
    float* __restrict__ cvec, int* __restrict__ deg, int t1, int t2, int N) {
    const int i = blockIdx.x * NTHR + threadIdx.x;
    if (i < N) deg[i] = 0;
    if (i < t1) {
        const int per = 2 * H * H;
        const int l = i / per;
        const int r = i - l * per;
        const int n = r % H;
        const int k = r / H;
        eW1t[(size_t)l * per + n * 2 * H + k] = f2bf(eW1[i]);
    } else if (i < t1 + t2) {
        const int j = i - t1;
        const int per = H * H;
        const int l = j / per;
        const int r = j - l * per;
        const int n = r % H;
        const int k = r / H;
        nW2t[(size_t)l * per + n * H + k] = f2bf(nW2[j]);
    } else if (i < t1 + 2 * t2) {
        const int j = i - t1 - t2;
        const int per = H * H;
        const int l = j / per;
        const int r = j - l * per;
        const int k = r / H;
        const int o = r % H;
        nW1tc[(size_t)l * H * 2 * H + o * 2 * H + k] =
            f2bf(nW1[(size_t)l * 2 * H * H + k * H + o]);
    } else {
        const int j = i - t1 - 2 * t2;
        const int per = (H + 1) * H;
        const int l = j / per;
        const int r = j - l * per;
        if (l >= t2 / (H * H)) return;  // l < L (t2 = L*H*H)
        const int jj = r / H;  // 0..128
        const int o = r % H;
        const float* w1 = nW1 + (size_t)l * 2 * H * H + (size_t)H * H;
        const float* row = (jj < H) ? (eW2 + (size_t)l * H * H + (size_t)jj * H)
                                    : (eb2 + (size_t)l * H);
        float s = 0.f;
#pragma unroll 4
        for (int c = 0; c < H; ++c) s = fmaf(row[c], w1[(size_t)c * H + o], s);
        if (jj < H)
            nW1tc[(size_t)l * H * 2 * H + o * 2 * H + H + jj] = f2bf(s);
        else
            cvec[(size_t)l * H + o] = s;
    }
}

// ----------------------- sort-by-dst machinery ----------------------------
__global__ __launch_bounds__(NTHR) void deg_kernel(const int* __restrict__ dst,
                                                   int* __restrict__ deg, int E) {
    const int e = blockIdx.x * NTHR + threadIdx.x;
    if (e < E) atomicAdd(&deg[dst[e]], 1);
}

__global__ __launch_bounds__(1024) void scan1_kernel(
    const int* __restrict__ deg, int* __restrict__ out,
    int* __restrict__ bsum, int N) {
    __shared__ int buf[1024];
    const int t = threadIdx.x;
    const int i = blockIdx.x * 1024 + t;
    const int x = (i < N) ? deg[i] : 0;
    buf[t] = x;
    __syncthreads();
    int v = x;
    for (int off = 1; off < 1024; off <<= 1) {
        const int y = (t >= off) ? buf[t - off] : 0;
        __syncthreads();
        v += y;
        buf[t] = v;
        __syncthreads();
    }
    if (i < N) out[i] = v - x;  // block-local exclusive
    if (t == 1023) bsum[blockIdx.x] = v;
}

__global__ void scan2_kernel(int* __restrict__ bsum, int nb) {
    if (threadIdx.x == 0) {
        int acc = 0;
        for (int i = 0; i < nb; ++i) {
            const int t = bsum[i];
            bsum[i] = acc;
            acc += t;
        }
    }
}

// also initializes chunkLo sentinel (saves a memset dispatch)
__global__ __launch_bounds__(NTHR) void scan3_kernel(
    int* __restrict__ out, int* __restrict__ cursor,
    const int* __restrict__ bsum, int* __restrict__ chunkLo, int N, int E,
    int numChunks) {
    const int i = blockIdx.x * NTHR + threadIdx.x;
    if (i < N) {
        const int v = out[i] + bsum[i >> 10];
        out[i] = v;
        cursor[i] = v;
    } else if (i == N) {
        out[N] = E;
    }
    if (i < numChunks) chunkLo[i] = 0x7fffffff;
}

// merged: chunkLo atomicMin + dst-sorted scatter
// srcS holds BYTE offsets into A (src * H * 2)
__global__ __launch_bounds__(NTHR) void finalize_kernel(
    const int* __restrict__ rowStart, int* __restrict__ chunkLo,
    const int* __restrict__ src, const int* __restrict__ dst,
    int* __restrict__ cursor, int* __restrict__ srcS, int N, int E) {
    const int i = blockIdx.x * NTHR + threadIdx.x;
    if (i < N) atomicMin(&chunkLo[rowStart[i] / CHUNK], i);
    if (i < E) {
        const int pos = atomicAdd(&cursor[dst[i]], 1);
        srcS[pos] = src[i] << 8;  // * 256 bytes per A row
    }
}

// ---------------- fp32 helper for encoder/decoder -------------------------
template <int K4>
__device__ __forceinline__ void mlp_layer(const float* __restrict__ W,
                                          const float* lds, int ldsStride,
                                          int c0, int egBase,
                                          float a0[8], float a1[8]) {
#pragma unroll 2
    for (int k4 = 0; k4 < K4; ++k4) {
        const float w00 = W[(k4 * 4 + 0) * H + c0];
        const float w01 = W[(k4 * 4 + 1) * H + c0];
        const float w02 = W[(k4 * 4 + 2) * H + c0];
        const float w03 = W[(k4 * 4 + 3) * H + c0];
        const float w10 = W[(k4 * 4 + 0) * H + c0 + 64];
        const float w11 = W[(k4 * 4 + 1) * H + c0 + 64];
        const float w12 = W[(k4 * 4 + 2) * H + c0 + 64];
        const float w13 = W[(k4 * 4 + 3) * H + c0 + 64];
#pragma unroll
        for (int e = 0; e < 8; ++e) {
            const float4 x = *reinterpret_cast<const float4*>(
                &lds[(egBase + e) * ldsStride + k4 * 4]);
            a0[e] = fmaf(x.x, w00, a0[e]);
            a0[e] = fmaf(x.y, w01, a0[e]);
            a0[e] = fmaf(x.z, w02, a0[e]);
            a0[e] = fmaf(x.w, w03, a0[e]);
            a1[e] = fmaf(x.x, w10, a1[e]);
            a1[e] = fmaf(x.y, w11, a1[e]);
            a1[e] = fmaf(x.z, w12, a1[e]);
            a1[e] = fmaf(x.w, w13, a1[e]);
        }
    }
}

// ---- FUSED encode+ab (32-row tile): nf -> h,h_bf; h_bf (LDS) -> A,B ------
// encode math identical to r10's encode_kernel (fp32); ab math identical to
// r10's ab_kernel on a 32-row tile. Bit-identical outputs.
__global__ __launch_bounds__(NTHR) void encab_kernel(
    const float* __restrict__ nf, const float* __restrict__ W1,
    const float* __restrict__ b1, const float* __restrict__ W2,
    const float* __restrict__ b2, float* __restrict__ h,
    unsigned short* __restrict__ h_bf,
    const unsigned short* __restrict__ eW1t,  // layer 0, [128 col][256 k]
    const float* __restrict__ eb1, unsigned short* __restrict__ A,
    float* __restrict__ Bout, int N) {
    __shared__ float xin[TILE * 16];                          // 2KB
    __shared__ float hm[TILE * H];                            // 16KB
    __shared__ __align__(16) unsigned short X[TILE * H];      // 8KB swizzled
    const int t = threadIdx.x;
    const int lane = t & 63;
    const int w = t >> 6;
    const int n0 = blockIdx.x * TILE;
    const int c0 = t & 63;
    const int eg = t >> 6;
    const int l15 = lane & 15;
    const int lq = lane >> 4;

    // ---- encode ----
    for (int i = t; i < TILE * 16; i += NTHR) {
        const int gi = n0 * 16 + i;
        xin[i] = (gi < N * 16) ? nf[gi] : 0.f;
    }
    __syncthreads();

    float a0[8], a1[8];
#pragma unroll
    for (int e = 0; e < 8; ++e) { a0[e] = 0.f; a1[e] = 0.f; }
    mlp_layer<4>(W1, xin, 16, c0, eg * 8, a0, a1);
    {
        const float bb0 = b1[c0], bb1 = b1[c0 + 64];
#pragma unroll
        for (int e = 0; e < 8; ++e) {
            hm[(eg * 8 + e) * H + c0] = gelu_fast(a0[e] + bb0);
            hm[(eg * 8 + e) * H + c0 + 64] = gelu_fast(a1[e] + bb1);
        }
    }
    __syncthreads();
#pragma unroll
    for (int e = 0; e < 8; ++e) { a0[e] = 0.f; a1[e] = 0.f; }
    mlp_layer<32>(W2, hm, H, c0, eg * 8, a0, a1);
    {
        const float bb0 = b2[c0], bb1 = b2[c0 + 64];
#pragma unroll
        for (int e = 0; e < 8; ++e) {
            const int row = eg * 8 + e;
            const int n = n0 + row;
            unsigned short hb0 = 0, hb1 = 0;
            if (n < N) {
                const float v0 = a0[e] + bb0, v1 = a1[e] + bb1;
                h[(size_t)n * H + c0] = v0;
                h[(size_t)n * H + c0 + 64] = v1;
                hb0 = f2bf(v0);
                hb1 = f2bf(v1);
                h_bf[(size_t)n * H + c0] = hb0;
                h_bf[(size_t)n * H + c0 + 64] = hb1;
            }
            // swizzled LDS (zeros for padded rows)
            const int bo0 = row * 256 + ((c0 * 2) ^ ((row & 7) << 4));
            const int bo1 = row * 256 + (((c0 + 64) * 2) ^ ((row & 7) << 4));
            *reinterpret_cast<unsigned short*>(reinterpret_cast<char*>(X) + bo0) = hb0;
            *reinterpret_cast<unsigned short*>(reinterpret_cast<char*>(X) + bo1) = hb1;
        }
    }

    // ---- ab (32 rows) ----
    const int half = w >> 1;  // 0 -> A (k 0..127), 1 -> B (k 128..255)
    const int cbase = (w & 1) * 64;
    bf16x8 Bf[4][4];
#pragma unroll
    for (int cg = 0; cg < 4; ++cg) {
        const int col = cbase + cg * 16 + l15;
#pragma unroll
        for (int s = 0; s < 4; ++s)
            Bf[cg][s] = *reinterpret_cast<const bf16x8*>(
                eW1t + (size_t)col * 256 + half * 128 + s * 32 + lq * 8);
    }
    __syncthreads();

    f32x4 acc[2][4];
#pragma unroll
    for (int rg = 0; rg < 2; ++rg)
#pragma unroll
        for (int cg = 0; cg < 4; ++cg) acc[rg][cg] = (f32x4)0.f;

#pragma unroll
    for (int s = 0; s < 4; ++s) {
        bf16x8 a[2];
#pragma unroll
        for (int rg = 0; rg < 2; ++rg) {
            const int row = rg * 16 + l15;
            const int byteoff = row * 256 + ((s * 64 + lq * 16) ^ ((row & 7) << 4));
            a[rg] = *reinterpret_cast<const bf16x8*>(
                reinterpret_cast<const char*>(X) + byteoff);
        }
#pragma unroll
        for (int rg = 0; rg < 2; ++rg)
#pragma unroll
            for (int cg = 0; cg < 4; ++cg)
                acc[rg][cg] = __builtin_amdgcn_mfma_f32_16x16x32_bf16(
                    a[rg], Bf[cg][s], acc[rg][cg], 0, 0, 0);
    }

#pragma unroll
    for (int cg = 0; cg < 4; ++cg) {
        const int col = cbase + cg * 16 + l15;
        const float bb = (half == 1) ? eb1[col] : 0.f;
#pragma unroll
        for (int rg = 0; rg < 2; ++rg) {
#pragma unroll
            for (int r = 0; r < 4; ++r) {
                const int row = rg * 16 + lq * 4 + r;
                const int n = n0 + row;
                if (n < N) {
                    if (half == 0)
                        A[(size_t)n * H + col] = f2bf(acc[rg][cg][r]);
                    else
                        Bout[(size_t)n * H + col] = acc[rg][cg][r] + bb;
                }
            }
        }
    }
}

// ---- edge gather: one wave per chunk, 2 cols/lane, 8-edge ILP window -----
__global__ __launch_bounds__(NTHR) void edge_gather_kernel(
    const unsigned short* __restrict__ A, const float* __restrict__ B,
    const int* __restrict__ srcS, const int* __restrict__ rowStart,  // N+1
    const int* __restrict__ chunkLo, unsigned short* __restrict__ aggB,
    int N, int E) {
    const int lane = threadIdx.x & 63;
    const int c = blockIdx.x * 4 + (threadIdx.x >> 6);
    const int nWaves = E / CHUNK + 1;
    if (c >= nWaves) return;
    int n = chunkLo[c];
    if (n >= N) return;  // sentinel: no node starts in this chunk
    const int Wend = (c + 1) * CHUNK;
    const int c2 = lane * 2;
    const char* Abase = (const char*)A + (size_t)(lane * 4);
    int r0 = rowStart[n];
    while (true) {
        const int r1 = rowStart[n + 1];
        const float2 bv = *reinterpret_cast<const float2*>(B + (size_t)n * H + c2);
        float s0 = 0.f, s1 = 0.f;
        int e = r0;
        for (; e + 8 <= r1; e += 8) {
            const int sa = srcS[e];
            const int sb = srcS[e + 1];
            const int sc = srcS[e + 2];
            const int sd = srcS[e + 3];
            const int se = srcS[e + 4];
            const int sf = srcS[e + 5];
            const int sg = srcS[e + 6];
            const int sh = srcS[e + 7];
            const unsigned int va = *reinterpret_cast<const unsigned int*>(Abase + sa);
            const unsigned int vb = *reinterpret_cast<const unsigned int*>(Abase + sb);
            const unsigned int vc = *reinterpret_cast<const unsigned int*>(Abase + sc);
            const unsigned int vd = *reinterpret_cast<const unsigned int*>(Abase + sd);
            const unsigned int ve = *reinterpret_cast<const unsigned int*>(Abase + se);
            const unsigned int vf = *reinterpret_cast<const unsigned int*>(Abase + sf);
            const unsigned int vg = *reinterpret_cast<const unsigned int*>(Abase + sg);
            const unsigned int vh = *reinterpret_cast<const unsigned int*>(Abase + sh);
            s0 += gelu_fast(bf2f_lo(va) + bv.x);
            s1 += gelu_fast(bf2f_hi(va) + bv.y);
            s0 += gelu_fast(bf2f_lo(vb) + bv.x);
            s1 += gelu_fast(bf2f_hi(vb) + bv.y);
            s0 += gelu_fast(bf2f_lo(vc) + bv.x);
            s1 += gelu_fast(bf2f_hi(vc) + bv.y);
            s0 += gelu_fast(bf2f_lo(vd) + bv.x);
            s1 += gelu_fast(bf2f_hi(vd) + bv.y);
            s0 += gelu_fast(bf2f_lo(ve) + bv.x);
            s1 += gelu_fast(bf2f_hi(ve) + bv.y);
            s0 += gelu_fast(bf2f_lo(vf) + bv.x);
            s1 += gelu_fast(bf2f_hi(vf) + bv.y);
            s0 += gelu_fast(bf2f_lo(vg) + bv.x);
            s1 += gelu_fast(bf2f_hi(vg) + bv.y);
            s0 += gelu_fast(bf2f_lo(vh) + bv.x);
            s1 += gelu_fast(bf2f_hi(vh) + bv.y);
        }
        for (; e + 4 <= r1; e += 4) {
            const int sa = srcS[e];
            const int sb = srcS[e + 1];
            const int sc = srcS[e + 2];
            const int sd = srcS[e + 3];
            const unsigned int va = *reinterpret_cast<const unsigned int*>(Abase + sa);
            const unsigned int vb = *reinterpret_cast<const unsigned int*>(Abase + sb);
            const unsigned int vc = *reinterpret_cast<const unsigned int*>(Abase + sc);
            const unsigned int vd = *reinterpret_cast<const unsigned int*>(Abase + sd);
            s0 += gelu_fast(bf2f_lo(va) + bv.x);
            s1 += gelu_fast(bf2f_hi(va) + bv.y);
            s0 += gelu_fast(bf2f_lo(vb) + bv.x);
            s1 += gelu_fast(bf2f_hi(vb) + bv.y);
            s0 += gelu_fast(bf2f_lo(vc) + bv.x);
            s1 += gelu_fast(bf2f_hi(vc) + bv.y);
            s0 += gelu_fast(bf2f_lo(vd) + bv.x);
            s1 += gelu_fast(bf2f_hi(vd) + bv.y);
        }
        for (; e < r1; ++e) {
            const unsigned int av =
                *reinterpret_cast<const unsigned int*>(Abase + srcS[e]);
            s0 += gelu_fast(bf2f_lo(av) + bv.x);
            s1 += gelu_fast(bf2f_hi(av) + bv.y);
        }
        const unsigned int packed =
            (unsigned int)f2bf(s0) | ((unsigned int)f2bf(s1) << 16);
        *reinterpret_cast<unsigned int*>(aggB + (size_t)n * H + c2) = packed;
        if (++n >= N) break;
        r0 = r1;
        if (r0 >= Wend) break;
    }
}

// ---- fused node update (+ next-layer A/B production) ---------------------
template <bool PROD>
__global__ __launch_bounds__(NTHR) void node_fused_kernel(
    float* __restrict__ h, unsigned short* __restrict__ h_bf,
    const unsigned short* __restrict__ aggB, const int* __restrict__ deg,
    const unsigned short* __restrict__ W1tc, const float* __restrict__ b1,
    const float* __restrict__ cvec, const unsigned short* __restrict__ W2t,
    const float* __restrict__ b2, const unsigned short* __restrict__ eW1tN,
    const float* __restrict__ eb1N, unsigned short* __restrict__ A_out,
    float* __restrict__ B_out, int N) {
    __shared__ __align__(16) unsigned short X[TE * 256];  // 32KB
    __shared__ int degS[TE];
    const int t = threadIdx.x;
    const int lane = t & 63;
    const int w = t >> 6;
    const int n0 = blockIdx.x * TE;
    const int l15 = lane & 15;
    const int lq = lane >> 4;

    if (t < TE) degS[t] = (n0 + t < N) ? deg[n0 + t] : 0;
#pragma unroll
    for (int i = 0; i < 8; ++i) {
        const int c = i * NTHR + t;
        const int row = c >> 5;
        const int col8 = c & 31;
        const int n = n0 + row;
        int4 v = make_int4(0, 0, 0, 0);
        if (n < N) {
            const unsigned short* srcp = (col8 < 16) ? h_bf : aggB;
            v = *reinterpret_cast<const int4*>(srcp + (size_t)n * H +
                                               (col8 & 15) * 8);
        }
        const int byteoff = row * 512 + ((col8 * 16) ^ ((row & 7) << 4));
        *reinterpret_cast<int4*>(reinterpret_cast<char*>(X) + byteoff) = v;
    }

    bf16x8 B1[2][8];
#pragma unroll
    for (int cg = 0; cg < 2; ++cg) {
        const int col = w * 32 + cg * 16 + l15;
#pragma unroll
        for (int s = 0; s < 8; ++s)
            B1[cg][s] = *reinterpret_cast<const bf16x8*>(
                W1tc + (size_t)col * 256 + s * 32 + lq * 8);
    }
    __syncthreads();

    f32x4 acc[4][2];
#pragma unroll
    for (int rg = 0; rg < 4; ++rg)
#pragma unroll
        for (int cg = 0; cg < 2; ++cg) acc[rg][cg] = (f32x4)0.f;

#pragma unroll
    for (int s = 0; s < 8; ++s) {
        bf16x8 a[4];
#pragma unroll
        for (int rg = 0; rg < 4; ++rg) {
            const int row = rg * 16 + l15;
            const int byteoff = row * 512 + ((s * 64 + lq * 16) ^ ((row & 7) << 4));
            a[rg] = *reinterpret_cast<const bf16x8*>(
                reinterpret_cast<const char*>(X) + byteoff);
        }
#pragma unroll
        for (int rg = 0; rg < 4; ++rg)
#pragma unroll
            for (int cg = 0; cg < 2; ++cg)
                acc[rg][cg] = __builtin_amdgcn_mfma_f32_16x16x32_bf16(
                    a[rg], B1[cg][s], acc[rg][cg], 0, 0, 0);
    }
    __syncthreads();

    // L1 epilogue: gelu(acc + b1 + deg*cvec) -> hm (LDS bytes 0..16K)
#pragma unroll
    for (int cg = 0; cg < 2; ++cg) {
        const int col = w * 32 + cg * 16 + l15;
        const float bb = b1[col];
        const float cc = cvec[col];
#pragma unroll
        for (int rg = 0; rg < 4; ++rg) {
#pragma unroll
            for (int r = 0; r < 4; ++r) {
                const int row = rg * 16 + lq * 4 + r;
                const float v =
                    gelu_fast(acc[rg][cg][r] + bb + (float)degS[row] * cc);
                const int byteoff = row * 256 + ((col * 2) ^ ((row & 7) << 4));
                *reinterpret_cast<unsigned short*>(
                    reinterpret_cast<char*>(X) + byteoff) = f2bf(v);
            }
        }
    }

    bf16x8 B2[2][4];
#pragma unroll
    for (int cg = 0; cg < 2; ++cg) {
        const int col = w * 32 + cg * 16 + l15;
#pragma unroll
        for (int s = 0; s < 4; ++s)
            B2[cg][s] = *reinterpret_cast<const bf16x8*>(
                W2t + (size_t)col * 128 + s * 32 + lq * 8);
    }
    __syncthreads();

    f32x4 acc2[4][2];
#pragma unroll
    for (int rg = 0; rg < 4; ++rg)
#pragma unroll
        for (int cg = 0; cg < 2; ++cg) acc2[rg][cg] = (f32x4)0.f;

#pragma unroll
    for (int s = 0; s < 4; ++s) {
        bf16x8 a[4];
#pragma unroll
        for (int rg = 0; rg < 4; ++rg) {
            const int row = rg * 16 + l15;
            const int byteoff = row * 256 + ((s * 64 + lq * 16) ^ ((row & 7) << 4));
            a[rg] = *reinterpret_cast<const bf16x8*>(
                reinterpret_cast<const char*>(X) + byteoff);
        }
#pragma unroll
        for (int rg = 0; rg < 4; ++rg)
#pragma unroll
            for (int cg = 0; cg < 2; ++cg)
                acc2[rg][cg] = __builtin_amdgcn_mfma_f32_16x16x32_bf16(
                    a[rg], B2[cg][s], acc2[rg][cg], 0, 0, 0);
    }

    // residual write: h += update; refresh h_bf; h_new bf16 -> LDS @16KB
#pragma unroll
    for (int cg = 0; cg < 2; ++cg) {
        const int col = w * 32 + cg * 16 + l15;
        const float bb = b2[col];
#pragma unroll
        for (int rg = 0; rg < 4; ++rg) {
#pragma unroll
            for (int r = 0; r < 4; ++r) {
                const int row = rg * 16 + lq * 4 + r;
                const int n = n0 + row;
                if (n < N) {
                    const float hv = h[(size_t)n * H + col] + acc2[rg][cg][r] + bb;
                    h[(size_t)n * H + col] = hv;
                    const unsigned short hb = f2bf(hv);
                    h_bf[(size_t)n * H + col] = hb;
                    if (PROD) {
                        const int byteoff =
                            16384 + row * 256 + ((col * 2) ^ ((row & 7) << 4));
                        *reinterpret_cast<unsigned short*>(
                            reinterpret_cast<char*>(X) + byteoff) = hb;
                    }
                } else if (PROD) {
                    const int byteoff =
                        16384 + row * 256 + ((col * 2) ^ ((row & 7) << 4));
                    *reinterpret_cast<unsigned short*>(
                        reinterpret_cast<char*>(X) + byteoff) = 0;
                }
            }
        }
    }

    if (PROD) {
        bf16x8 B3[2][4], B4[2][4];
#pragma unroll
        for (int cg = 0; cg < 2; ++cg) {
            const int col = w * 32 + cg * 16 + l15;
#pragma unroll
            for (int s = 0; s < 4; ++s) {
                B3[cg][s] = *reinterpret_cast<const bf16x8*>(
                    eW1tN + (size_t)col * 256 + s * 32 + lq * 8);
                B4[cg][s] = *reinterpret_cast<const bf16x8*>(
                    eW1tN + (size_t)col * 256 + 128 + s * 32 + lq * 8);
            }
        }
        __syncthreads();

        f32x4 acc3[4][2], acc4[4][2];
#pragma unroll
        for (int rg = 0; rg < 4; ++rg)
#pragma unroll
            for (int cg = 0; cg < 2; ++cg) {
                acc3[rg][cg] = (f32x4)0.f;
                acc4[rg][cg] = (f32x4)0.f;
            }

#pragma unroll
        for (int s = 0; s < 4; ++s) {
            bf16x8 a[4];
#pragma unroll
            for (int rg = 0; rg < 4; ++rg) {
                const int row = rg * 16 + l15;
                const int byteoff =
                    16384 + row * 256 + ((s * 64 + lq * 16) ^ ((row & 7) << 4));
                a[rg] = *reinterpret_cast<const bf16x8*>(
                    reinterpret_cast<const char*>(X) + byteoff);
            }
#pragma unroll
            for (int rg = 0; rg < 4; ++rg)
#pragma unroll
                for (int cg = 0; cg < 2; ++cg) {
                    acc3[rg][cg] = __builtin_amdgcn_mfma_f32_16x16x32_bf16(
                        a[rg], B3[cg][s], acc3[rg][cg], 0, 0, 0);
                    acc4[rg][cg] = __builtin_amdgcn_mfma_f32_16x16x32_bf16(
                        a[rg], B4[cg][s], acc4[rg][cg], 0, 0, 0);
                }
        }

#pragma unroll
        for (int cg = 0; cg < 2; ++cg) {
            const int col = w * 32 + cg * 16 + l15;
            const float bb = eb1N[col];
#pragma unroll
            for (int rg = 0; rg < 4; ++rg) {
#pragma unroll
                for (int r = 0; r < 4; ++r) {
                    const int row = rg * 16 + lq * 4 + r;
                    const int n = n0 + row;
                    if (n < N) {
                        A_out[(size_t)n * H + col] = f2bf(acc3[rg][cg][r]);
                        B_out[(size_t)n * H + col] = acc4[rg][cg][r] + bb;
                    }
                }
            }
        }
    }
}

// --------------- decoder: h -> GELU MLP -> out [N,8] ----------------------
__global__ __launch_bounds__(NTHR) void decode_kernel(
    const float* __restrict__ h, const float* __restrict__ W1,
    const float* __restrict__ b1, const float* __restrict__ W2,
    const float* __restrict__ b2, float* __restrict__ out, int N) {
    __shared__ float xin[TILE * H];
    __shared__ float hm[TILE * 132];
    const int t = threadIdx.x;
    const int n0 = blockIdx.x * TILE;
    const int c0 = t & 63;
    const int eg = t >> 6;
    {
        const int col = t & 127;
        for (int e = t >> 7; e < TILE; e += 2) {
            const int n = n0 + e;
            xin[e * H + col] = (n < N) ? h[(size_t)n * H + col] : 0.f;
        }
    }
    __syncthreads();

    float a0[8], a1[8];
#pragma unroll
    for (int e = 0; e < 8; ++e) { a0[e] = 0.f; a1[e] = 0.f; }
    mlp_layer<32>(W1, xin, H, c0, eg * 8, a0, a1);
    {
        const float bb0 = b1[c0], bb1 = b1[c0 + 64];
#pragma unroll
        for (int e = 0; e < 8; ++e) {
            hm[(eg * 8 + e) * 132 + c0] = gelu_fast(a0[e] + bb0);
            hm[(eg * 8 + e) * 132 + c0 + 64] = gelu_fast(a1[e] + bb1);
        }
    }
    __syncthreads();
    {
        const int e = t >> 3;
        const int o = t & 7;
        const int n = n0 + e;
        float acc = b2[o];
#pragma unroll 4
        for (int k = 0; k < H; ++k)
            acc = fmaf(hm[e * 132 + k], W2[k * 8 + o], acc);
        if (n < N) out[n * 8 + o] = acc;
    }
}

extern "C" void kernel_launch(void* const* d_in, const int* in_sizes, int n_in,
                              void* d_out, int out_size, void* d_ws,
                              size_t ws_size, hipStream_t stream) {
    (void)n_in; (void)out_size; (void)ws_size;
    const float* nf      = (const float*)d_in[0];
    const int*   ei      = (const int*)d_in[1];
    const float* enc_W1  = (const float*)d_in[2];
    const float* enc_b1  = (const float*)d_in[3];
    const float* enc_W2  = (const float*)d_in[4];
    const float* enc_b2  = (const float*)d_in[5];
    const float* edge_W1 = (const float*)d_in[6];
    const float* edge_b1 = (const float*)d_in[7];
    const float* edge_W2 = (const float*)d_in[8];
    const float* edge_b2 = (const float*)d_in[9];
    const float* node_W1 = (const float*)d_in[10];
    const float* node_b1 = (const float*)d_in[11];
    const float* node_W2 = (const float*)d_in[12];
    const float* node_b2 = (const float*)d_in[13];
    const float* dec_W1  = (const float*)d_in[14];
    const float* dec_b1  = (const float*)d_in[15];
    const float* dec_W2  = (const float*)d_in[16];
    const float* dec_b2  = (const float*)d_in[17];

    const int N = in_sizes[0] / 16;
    const int E = in_sizes[1] / 2;
    const int L = in_sizes[7] / H;  // edge_b1 is [L,H]
    const int numChunks = E / CHUNK + 1;

    // ---------------- workspace layout ----------------
    char* ws = (char*)d_ws;
    float* h    = (float*)ws;                    ws += (size_t)N * H * 4;
    float* Bf32 = (float*)ws;                    ws += (size_t)N * H * 4;
    unsigned short* h_bf = (unsigned short*)ws;  ws += (size_t)N * H * 2;
    unsigned short* A_bf = (unsigned short*)ws;  ws += (size_t)N * H * 2;
    unsigned short* aggB = (unsigned short*)ws;  ws += (size_t)N * H * 2;
    int* srcS     = (int*)ws;                    ws += (size_t)E * 4;
    int* deg      = (int*)ws;                    ws += (size_t)N * 4;
    int* rowStart = (int*)ws;                    ws += (size_t)(N + 1) * 4;
    int* cursor   = (int*)ws;                    ws += (size_t)N * 4;
    int* bsum     = (int*)ws;                    ws += (size_t)256 * 4;
    int* chunkLo  = (int*)ws;                    ws += (size_t)numChunks * 4;
    unsigned short* eW1t = (unsigned short*)ws;  ws += (size_t)L * 2 * H * H * 2;
    unsigned short* nW1tc = (unsigned short*)ws; ws += (size_t)L * 2 * H * H * 2;
    unsigned short* nW2t = (unsigned short*)ws;  ws += (size_t)L * H * H * 2;
    float* cvec   = (float*)ws;                  ws += (size_t)L * H * 4;

    const int* srcArr = ei;
    const int* dstArr = ei + E;

    // ---- merged weight prep + wcomb + deg zeroing (one dispatch) ----
    {
        const int t1 = L * 2 * H * H, t2 = L * H * H;
        const int total = t1 + 2 * t2 + L * (H + 1) * H;
        prep_kernel<<<(total + NTHR - 1) / NTHR, NTHR, 0, stream>>>(
            edge_W1, node_W2, node_W1, edge_W2, edge_b2, eW1t, nW2t, nW1tc,
            cvec, deg, t1, t2, N);
    }

    // ---- sort edges by dst (hist + multiblock scan + merged finalize) ----
    deg_kernel<<<(E + NTHR - 1) / NTHR, NTHR, 0, stream>>>(dstArr, deg, E);
    const int nScanB = (N + 1023) / 1024;
    scan1_kernel<<<nScanB, 1024, 0, stream>>>(deg, rowStart, bsum, N);
    scan2_kernel<<<1, 64, 0, stream>>>(bsum, nScanB);
    const int scan3Span = (N + 1 > numChunks) ? (N + 1) : numChunks;
    scan3_kernel<<<(scan3Span + NTHR - 1) / NTHR, NTHR, 0, stream>>>(
        rowStart, cursor, bsum, chunkLo, N, E, numChunks);
    const int finSpan = (N > E) ? N : E;
    finalize_kernel<<<(finSpan + NTHR - 1) / NTHR, NTHR, 0, stream>>>(
        rowStart, chunkLo, srcArr, dstArr, cursor, srcS, N, E);

    const int encBlocks  = (N + TILE - 1) / TILE;
    const int tileBlocks = (N + TE - 1) / TE;
    const int gatherBlks = (numChunks + 3) / 4;

    // fused encode + layer-0 A/B production
    encab_kernel<<<encBlocks, NTHR, 0, stream>>>(
        nf, enc_W1, enc_b1, enc_W2, enc_b2, h, h_bf, eW1t, edge_b1, A_bf,
        Bf32, N);
    for (int l = 0; l < L; ++l) {
        edge_gather_kernel<<<gatherBlks, NTHR, 0, stream>>>(
            A_bf, Bf32, srcS, rowStart, chunkLo, aggB, N, E);
        if (l + 1 < L) {
            node_fused_kernel<true><<<tileBlocks, NTHR, 0, stream>>>(
                h, h_bf, aggB, deg, nW1tc + (size_t)l * 2 * H * H,
                node_b1 + (size_t)l * H, cvec + (size_t)l * H,
                nW2t + (size_t)l * H * H, node_b2 + (size_t)l * H,
                eW1t + (size_t)(l + 1) * 2 * H * H,
                edge_b1 + (size_t)(l + 1) * H, A_bf, Bf32, N);
        } else {
            node_fused_kernel<false><<<tileBlocks, NTHR, 0, stream>>>(
                h, h_bf, aggB, deg, nW1tc + (size_t)l * 2 * H * H,
                node_b1 + (size_t)l * H, cvec + (size_t)l * H,
                nW2t + (size_t)l * H * H, node_b2 + (size_t)l * H, nullptr,
                nullptr, nullptr, nullptr, N);
        }
    }
    decode_kernel<<<encBlocks, NTHR, 0, stream>>>(h, dec_W1, dec_b1, dec_W2,
                                                  dec_b2, (float*)d_out, N);
}